// Round 13
// baseline (238.432 us; speedup 1.0000x reference)
//
#include <hip/hip_runtime.h>
#include <hip/hip_bf16.h>
#include <math.h>

using bf16 = __hip_bfloat16;
typedef __attribute__((ext_vector_type(8))) short bf16x8;
typedef __attribute__((ext_vector_type(4))) float f32x4;

#define BB   4
#define TT   2048
#define DD   1024
#define HH   16
#define HD_  64
#define LAT_ 128
#define RP   32
#define EPS_ 1e-6f
// 0.125 (1/sqrt(64)) * log2(e): folded into qn so attn can use exp2
#define QSCALE_ 0.18033688011112042f

static __device__ __forceinline__ void stf(float* p, float v) { *p = v; }
static __device__ __forceinline__ void stf(bf16* p, float v) { *p = __float2bfloat16(v); }

// global -> LDS 16B DMA (wave-uniform LDS base + lane*16)
static __device__ __forceinline__ void gl2lds16(const void* g, void* l)
{
    __builtin_amdgcn_global_load_lds(
        (const __attribute__((address_space(1))) void*)g,
        (__attribute__((address_space(3))) void*)l, 16, 0, 0);
}

__global__ __launch_bounds__(256)
void sentinel_kernel(float* __restrict__ out, float val, long long n)
{
    long long i = (long long)blockIdx.x * 256 + threadIdx.x;
    if (i < n) out[i] = val;
}

// ---------------------------------------------------------------------------
// Converters
// ---------------------------------------------------------------------------
__global__ __launch_bounds__(256)
void conv_x_kernel(const float* __restrict__ x, bf16* __restrict__ xb, long long n4)
{
    long long i = (long long)blockIdx.x * 256 + threadIdx.x;
    if (i >= n4) return;
    float4 v = *(const float4*)(x + i * 4);
    union { bf16 h[4]; uint2 u; } o;
    o.h[0] = __float2bfloat16(v.x);
    o.h[1] = __float2bfloat16(v.y);
    o.h[2] = __float2bfloat16(v.z);
    o.h[3] = __float2bfloat16(v.w);
    *(uint2*)(xb + i * 4) = o.u;
}

// Tiled transpose-convert: W (K x N fp32 row-major) -> WT (N x K bf16).
__global__ __launch_bounds__(256)
void conv_trans_kernel(const float* __restrict__ W, bf16* __restrict__ WT,
                       int K, int N)
{
    __shared__ __align__(16) bf16 t[64][72];
    const int k0 = blockIdx.y * 64, n0 = blockIdx.x * 64;
    const int tid = threadIdx.x;
    const int r = tid >> 2, c0 = (tid & 3) * 16;
    const float* src = W + (size_t)(k0 + r) * N + n0 + c0;
    #pragma unroll
    for (int j = 0; j < 16; j += 4) {
        float4 v = *(const float4*)(src + j);
        t[c0 + j + 0][r] = __float2bfloat16(v.x);
        t[c0 + j + 1][r] = __float2bfloat16(v.y);
        t[c0 + j + 2][r] = __float2bfloat16(v.z);
        t[c0 + j + 3][r] = __float2bfloat16(v.w);
    }
    __syncthreads();
    const int rr = tid >> 2, cc = (tid & 3) * 16;
    bf16* dst = WT + (size_t)(n0 + rr) * K + k0 + cc;
    *(bf16x8*)dst       = *(const bf16x8*)&t[rr][cc];
    *(bf16x8*)(dst + 8) = *(const bf16x8*)&t[rr][cc + 8];
}

// [Wk | Wv] (each 128x512) -> WT (1024 x 128).
__global__ __launch_bounds__(256)
void conv_wkwv_kernel(const float* __restrict__ Wk, const float* __restrict__ Wv,
                      bf16* __restrict__ WT)
{
    int idx = blockIdx.x * 256 + threadIdx.x;      // 128*1024
    if (idx >= 128 * 1024) return;
    int k = idx >> 10, n = idx & 1023;
    float v = (n < 512) ? Wk[k * 512 + n] : Wv[k * 512 + (n - 512)];
    WT[(size_t)n * 128 + k] = __float2bfloat16(v);
}

// Wo (1024x1024) -> woT (1024 x 512) tiled transpose with row remap.
__global__ __launch_bounds__(256)
void conv_woT_kernel(const float* __restrict__ Wo, bf16* __restrict__ WT)
{
    __shared__ __align__(16) bf16 t[64][72];
    const int mm0 = blockIdx.y * 64, n0 = blockIdx.x * 64;
    const int tid = threadIdx.x;
    const int r = tid >> 2, c0 = (tid & 3) * 16;
    const int mm = mm0 + r;
    const int row = ((mm >> 5) << 6) | (mm & 31);
    const float* src = Wo + (size_t)row * 1024 + n0 + c0;
    #pragma unroll
    for (int j = 0; j < 16; j += 4) {
        float4 v = *(const float4*)(src + j);
        t[c0 + j + 0][r] = __float2bfloat16(v.x);
        t[c0 + j + 1][r] = __float2bfloat16(v.y);
        t[c0 + j + 2][r] = __float2bfloat16(v.z);
        t[c0 + j + 3][r] = __float2bfloat16(v.w);
    }
    __syncthreads();
    const int rr = tid >> 2, cc = (tid & 3) * 16;
    bf16* dst = WT + (size_t)(n0 + rr) * 512 + mm0 + cc;
    *(bf16x8*)dst       = *(const bf16x8*)&t[rr][cc];
    *(bf16x8*)(dst + 8) = *(const bf16x8*)&t[rr][cc + 8];
}

// ---------------------------------------------------------------------------
// MFMA GEMM with global_load_lds staging. C[M,N] = A @ B, A bf16 (M x K)
// row-major, BT bf16 (N x K) row-major. 128x128 tile, BK=32.
// Fragment maps (HW-verified): A[m=lane&15][k=quad*8+j],
// BT[n=lane&15][k=quad*8+j], C/D row=quad*4+reg, col=lane&15.
// ---------------------------------------------------------------------------
#define GEMM_PROLOG_128 \
    __shared__ __align__(16) short As[128][32]; \
    __shared__ __align__(16) short Bs[128][32]; \
    const int tid  = threadIdx.x; \
    const int wave = tid >> 6, lane = tid & 63; \
    const int quad = lane >> 4, l16 = lane & 15; \
    const int wr = (wave >> 1) * 64, wc = (wave & 1) * 64; \
    const int row0 = blockIdx.y * 128, col0 = blockIdx.x * 128; \
    const int srow = tid >> 2, scol = (tid & 3) * 8; \
    char* lAs0 = (char*)As + wave * 1024; \
    char* lAs1 = (char*)As + 4096 + wave * 1024; \
    char* lBs0 = (char*)Bs + wave * 1024; \
    char* lBs1 = (char*)Bs + 4096 + wave * 1024; \
    f32x4 acc[4][4]; \
    _Pragma("unroll") \
    for (int mt = 0; mt < 4; ++mt) \
        _Pragma("unroll") \
        for (int nt = 0; nt < 4; ++nt) \
            acc[mt][nt] = (f32x4){0.f, 0.f, 0.f, 0.f}; \
    for (int k0 = 0; k0 < K; k0 += 32) { \
        const short* ga = A  + (size_t)(row0 + srow) * K + k0 + scol; \
        const short* gb = BT + (size_t)(col0 + srow) * K + k0 + scol; \
        __syncthreads(); \
        gl2lds16(ga,                  lAs0); \
        gl2lds16(ga + (size_t)64 * K, lAs1); \
        gl2lds16(gb,                  lBs0); \
        gl2lds16(gb + (size_t)64 * K, lBs1); \
        __syncthreads(); \
        bf16x8 af[4], bfv[4]; \
        _Pragma("unroll") \
        for (int mt = 0; mt < 4; ++mt) \
            af[mt] = *(const bf16x8*)&As[wr + mt * 16 + l16][quad * 8]; \
        _Pragma("unroll") \
        for (int nt = 0; nt < 4; ++nt) \
            bfv[nt] = *(const bf16x8*)&Bs[wc + nt * 16 + l16][quad * 8]; \
        _Pragma("unroll") \
        for (int mt = 0; mt < 4; ++mt) \
            _Pragma("unroll") \
            for (int nt = 0; nt < 4; ++nt) \
                acc[mt][nt] = __builtin_amdgcn_mfma_f32_16x16x32_bf16( \
                    af[mt], bfv[nt], acc[mt][nt], 0, 0, 0); \
    }

template <typename OT>
__global__ __launch_bounds__(256)
void gemm_mfma(const short* __restrict__ A, const short* __restrict__ BT,
               OT* __restrict__ C, int M, int N, int K)
{
    GEMM_PROLOG_128
    #pragma unroll
    for (int mt = 0; mt < 4; ++mt)
        #pragma unroll
        for (int nt = 0; nt < 4; ++nt) {
            const int col = col0 + wc + nt * 16 + l16;
            #pragma unroll
            for (int r = 0; r < 4; ++r) {
                const int row = row0 + wr + mt * 16 + quad * 4 + r;
                stf(C + (size_t)row * N + col, acc[mt][nt][r]);
            }
        }
}

// ---------------------------------------------------------------------------
// GEMM1 + fused Q-RMSNorm epilogue. qn pre-scaled by 0.125*log2(e) so the
// attention can use exp2 directly.
// ---------------------------------------------------------------------------
__global__ __launch_bounds__(256)
void gemm_qrms(const short* __restrict__ A, const short* __restrict__ BT,
               bf16* __restrict__ qn, const float* __restrict__ qg,
               int M, int N, int K)
{
    GEMM_PROLOG_128
    const int h = (col0 + wc) >> 6;
    const float g0 = qg[l16], g1 = qg[16 + l16];
    #pragma unroll
    for (int mt = 0; mt < 4; ++mt) {
        float ss[4];
        #pragma unroll
        for (int r = 0; r < 4; ++r)
            ss[r] = acc[mt][0][r] * acc[mt][0][r] + acc[mt][1][r] * acc[mt][1][r]
                  + acc[mt][2][r] * acc[mt][2][r] + acc[mt][3][r] * acc[mt][3][r];
        #pragma unroll
        for (int off = 1; off < 16; off <<= 1)
            #pragma unroll
            for (int r = 0; r < 4; ++r) ss[r] += __shfl_xor(ss[r], off, 64);
        #pragma unroll
        for (int r = 0; r < 4; ++r) {
            const float inv = QSCALE_ / sqrtf(ss[r] * (1.0f / HD_) + EPS_);
            const int row = row0 + wr + mt * 16 + quad * 4 + r;
            const int b = row >> 11, t = row & 2047;
            bf16* op = qn + (((size_t)(b * HH + h)) * TT + t) * RP;
            op[l16]      = __float2bfloat16(g0 * acc[mt][0][r] * inv);
            op[16 + l16] = __float2bfloat16(g1 * acc[mt][1][r] * inv);
        }
    }
}

// ---------------------------------------------------------------------------
// GEMM4 + fused K-RMSNorm / V-split epilogue. V path writes vT (bh,32,2048)
// DIRECTLY (transposed), eliminating the vtrans kernel: per (mt,nt) one
// packed 8B store of 4 consecutive t values.
// ---------------------------------------------------------------------------
struct __attribute__((aligned(8))) bf4 { bf16 v[4]; };

__global__ __launch_bounds__(256)
void gemm_kv(const short* __restrict__ A, const short* __restrict__ BT,
             bf16* __restrict__ kn, bf16* __restrict__ vT,
             const float* __restrict__ kg, int M, int N, int K)
{
    GEMM_PROLOG_128
    const int colbase = col0 + wc;
    if (colbase < 512) {                        // K-RMS path
        const int h0 = colbase >> 5;            // groups h0, h0+1
        const float g0 = kg[l16], g1 = kg[16 + l16];
        #pragma unroll
        for (int mt = 0; mt < 4; ++mt) {
            float s0[4], s1[4];
            #pragma unroll
            for (int r = 0; r < 4; ++r) {
                s0[r] = acc[mt][0][r] * acc[mt][0][r] + acc[mt][1][r] * acc[mt][1][r];
                s1[r] = acc[mt][2][r] * acc[mt][2][r] + acc[mt][3][r] * acc[mt][3][r];
            }
            #pragma unroll
            for (int off = 1; off < 16; off <<= 1)
                #pragma unroll
                for (int r = 0; r < 4; ++r) {
                    s0[r] += __shfl_xor(s0[r], off, 64);
                    s1[r] += __shfl_xor(s1[r], off, 64);
                }
            #pragma unroll
            for (int r = 0; r < 4; ++r) {
                const float i0 = 1.0f / sqrtf(s0[r] * (1.0f / RP) + EPS_);
                const float i1 = 1.0f / sqrtf(s1[r] * (1.0f / RP) + EPS_);
                const int row = row0 + wr + mt * 16 + quad * 4 + r;
                const int b = row >> 11, t = row & 2047;
                bf16* op0 = kn + (((size_t)(b * HH + h0)) * TT + t) * RP;
                bf16* op1 = kn + (((size_t)(b * HH + h0 + 1)) * TT + t) * RP;
                op0[l16]      = __float2bfloat16(g0 * acc[mt][0][r] * i0);
                op0[16 + l16] = __float2bfloat16(g1 * acc[mt][1][r] * i0);
                op1[l16]      = __float2bfloat16(g0 * acc[mt][2][r] * i1);
                op1[16 + l16] = __float2bfloat16(g1 * acc[mt][3][r] * i1);
            }
        }
    } else {                                     // V path -> transposed vT
        const int h0 = (colbase - 512) >> 5;
        #pragma unroll
        for (int mt = 0; mt < 4; ++mt)
            #pragma unroll
            for (int nt = 0; nt < 4; ++nt) {
                const int h = h0 + (nt >> 1);
                const int c = (nt & 1) * 16 + l16;
                const int row = row0 + wr + mt * 16 + quad * 4;   // r=0 base
                const int b = row >> 11, t = row & 2047;
                bf4 pk;
                #pragma unroll
                for (int r = 0; r < 4; ++r)
                    pk.v[r] = __float2bfloat16(acc[mt][nt][r]);
                *(bf4*)(vT + (((size_t)(b * HH + h)) * RP + c) * TT + t) = pk;
            }
    }
}

// ---------------------------------------------------------------------------
// 64x128-tile GEMM (gemm3: 8192x128, K=1024 -> 128 blocks).
// ---------------------------------------------------------------------------
__global__ __launch_bounds__(256)
void gemm_k64(const short* __restrict__ A, const short* __restrict__ BT,
              bf16* __restrict__ C, int M, int N, int K)
{
    __shared__ __align__(16) short As[64][32];
    __shared__ __align__(16) short Bs[128][32];
    const int tid  = threadIdx.x;
    const int wave = tid >> 6, lane = tid & 63;
    const int quad = lane >> 4, l16 = lane & 15;
    const int wr = (wave >> 1) * 32, wc = (wave & 1) * 64;
    const int row0 = blockIdx.y * 64, col0 = blockIdx.x * 128;
    const int srow = tid >> 2, scol = (tid & 3) * 8;

    char* lAs  = (char*)As + wave * 1024;
    char* lBs0 = (char*)Bs + wave * 1024;
    char* lBs1 = (char*)Bs + 4096 + wave * 1024;

    f32x4 acc[2][4];
    #pragma unroll
    for (int mt = 0; mt < 2; ++mt)
        #pragma unroll
        for (int nt = 0; nt < 4; ++nt)
            acc[mt][nt] = (f32x4){0.f, 0.f, 0.f, 0.f};

    for (int k0 = 0; k0 < K; k0 += 32) {
        const short* ga = A  + (size_t)(row0 + srow) * K + k0 + scol;
        const short* gb = BT + (size_t)(col0 + srow) * K + k0 + scol;
        __syncthreads();
        gl2lds16(ga,                  lAs);
        gl2lds16(gb,                  lBs0);
        gl2lds16(gb + (size_t)64 * K, lBs1);
        __syncthreads();

        bf16x8 af[2], bfv[4];
        #pragma unroll
        for (int mt = 0; mt < 2; ++mt)
            af[mt] = *(const bf16x8*)&As[wr + mt * 16 + l16][quad * 8];
        #pragma unroll
        for (int nt = 0; nt < 4; ++nt)
            bfv[nt] = *(const bf16x8*)&Bs[wc + nt * 16 + l16][quad * 8];
        #pragma unroll
        for (int mt = 0; mt < 2; ++mt)
            #pragma unroll
            for (int nt = 0; nt < 4; ++nt)
                acc[mt][nt] = __builtin_amdgcn_mfma_f32_16x16x32_bf16(
                    af[mt], bfv[nt], acc[mt][nt], 0, 0, 0);
    }

    #pragma unroll
    for (int mt = 0; mt < 2; ++mt)
        #pragma unroll
        for (int nt = 0; nt < 4; ++nt) {
            const int col = col0 + wc + nt * 16 + l16;
            #pragma unroll
            for (int r = 0; r < 4; ++r) {
                const int row = row0 + wr + mt * 16 + quad * 4 + r;
                C[(size_t)row * N + col] = __float2bfloat16(acc[mt][nt][r]);
            }
        }
}

// ---------------------------------------------------------------------------
// Flash MFMA attention v8: cooperative dbuf LDS staging + XOR swizzle +
// PAIRED-TILE SINGLE SWEEP. Since NT_A=2bx+2 < NT_B=32-2bx always, both
// paired q-tiles (bx, 15-bx) share ONE staged KV sweep over tile B's
// range; tile A computes only while st < NT_A (block-uniform branch).
// Staging DMAs/barriers drop 34 -> avg 25 per block; compute per staged
// byte ~doubles (hides DMA better); MFMA work unchanged.
// P_lds reused sequentially per wave (wave-local RAW via lgkmcnt).
// exp2f (qn pre-scaled by log2e) -> bare v_exp_f32.
// ---------------------------------------------------------------------------
#define ATTN_TILE(QF, QB, LSUM, OA, OB)                                         \
    {                                                                           \
        f32x4 sc[4];                                                            \
        _Pragma("unroll")                                                       \
        for (int sub = 0; sub < 4; ++sub) {                                     \
            bf16x8 kf = *(const bf16x8*)&KsC[(sub * 16 + l16) * 32              \
                                             + ((quad ^ kslot) * 8)];           \
            sc[sub] = __builtin_amdgcn_mfma_f32_16x16x32_bf16(                  \
                kf, QF, (f32x4){0.f, 0.f, 0.f, 0.f}, 0, 0, 0);                  \
        }                                                                       \
        if (s0 + 63 > (QB)) {                                                   \
            const int qg_ = (QB) + l16;                                         \
            _Pragma("unroll")                                                   \
            for (int sub = 0; sub < 4; ++sub)                                   \
                _Pragma("unroll")                                               \
                for (int r = 0; r < 4; ++r)                                     \
                    if (s0 + sub * 16 + quad * 4 + r > qg_) sc[sub][r] = -1e30f;\
        }                                                                       \
        _Pragma("unroll")                                                       \
        for (int sub = 0; sub < 4; ++sub) {                                     \
            const float p0 = exp2f(sc[sub][0]);                                 \
            const float p1 = exp2f(sc[sub][1]);                                 \
            const float p2 = exp2f(sc[sub][2]);                                 \
            const float p3 = exp2f(sc[sub][3]);                                 \
            bf4 pk;                                                             \
            pk.v[0] = __float2bfloat16(p0);                                     \
            pk.v[1] = __float2bfloat16(p1);                                     \
            pk.v[2] = __float2bfloat16(p2);                                     \
            pk.v[3] = __float2bfloat16(p3);                                     \
            *(bf4*)&P_lds[w8][l16][sub * 16 + quad * 4] = pk;                   \
            LSUM += (p0 + p1) + (p2 + p3);                                      \
        }                                                                       \
        _Pragma("unroll")                                                       \
        for (int ks = 0; ks < 2; ++ks) {                                        \
            bf16x8 pf  = *(const bf16x8*)&P_lds[w8][l16][ks * 32 + quad * 8];   \
            bf16x8 vf0 = *(const bf16x8*)&VsC[l16 * 64                          \
                            + (((ks * 4 + quad) ^ vswz) * 8)];                  \
            bf16x8 vf1 = *(const bf16x8*)&VsC[(16 + l16) * 64                   \
                            + (((ks * 4 + quad) ^ vswz) * 8)];                  \
            OA = __builtin_amdgcn_mfma_f32_16x16x32_bf16(pf, vf0, OA, 0, 0, 0); \
            OB = __builtin_amdgcn_mfma_f32_16x16x32_bf16(pf, vf1, OB, 0, 0, 0); \
        }                                                                       \
    }

#define ATTN_EPI(QB, LSUM, OA, OB)                                              \
    {                                                                           \
        float ls_ = (LSUM);                                                     \
        ls_ += __shfl_xor(ls_, 16, 64);                                         \
        ls_ += __shfl_xor(ls_, 32, 64);                                         \
        _Pragma("unroll")                                                       \
        for (int r = 0; r < 4; ++r) {                                           \
            const float lr  = __shfl(ls_, quad * 20 + r, 64);                   \
            const float inv = 1.0f / lr;                                        \
            const int t = (QB) + quad * 4 + r;                                  \
            bf16* op = att + ((size_t)(b * TT + t)) * 512 + h * 32;             \
            op[l16]      = __float2bfloat16((OA)[r] * inv);                     \
            op[16 + l16] = __float2bfloat16((OB)[r] * inv);                     \
        }                                                                       \
    }

__global__ __launch_bounds__(512, 4)
void attn_mfma(const bf16* __restrict__ qn, const bf16* __restrict__ kn,
               const bf16* __restrict__ vT, bf16* __restrict__ att)
{
    __shared__ __align__(16) short KsF[2][64 * 32];   // 8 KB, swizzled slots
    __shared__ __align__(16) short VsF[2][32 * 64];   // 8 KB, swizzled slots
    __shared__ __align__(16) bf16 P_lds[8][16][72];   // 18 KB
    const int tid  = threadIdx.x;
    const int w8   = tid >> 6, lane = tid & 63;
    const int quad = lane >> 4, l16 = lane & 15;
    // XCD-aware bijective remap: f -> (bx 0..7, bh 0..63), bh%8 == xcd
    const int f  = (int)(blockIdx.y * 8 + blockIdx.x);     // 0..511
    const int xr = f & 7, j = f >> 3;                       // j: 0..63
    const int bx = j & 7;
    const int bh = xr + 8 * (j >> 3);
    const int b = bh >> 4, h = bh & 15;

    const bf16* knb = kn + (size_t)bh * TT * RP;
    const bf16* vtb = vT + (size_t)bh * RP * TT;

    // staging map (LDS dest linear within buffer; source pre-swizzled):
    // K chunk c (=tid, waves 0-3): row=c>>2, gslot=(c&3)^((c>>3)&3)
    // V chunk c (=tid-256, waves 4-7): row=c>>3, gslot=(c&7)^((c>>3)&7)
    const bool isK = (w8 < 4);
    const int  cK = tid;
    const int  cV = tid - 256;
    const bf16* sBase = isK
        ? knb + (size_t)(cK >> 2) * RP + ((cK & 3) ^ ((cK >> 3) & 3)) * 8
        : vtb + (size_t)(cV >> 3) * TT + ((cV & 7) ^ ((cV >> 3) & 7)) * 8;
    const long long sStep = (long long)(isK ? RP : 1) * 64;  // per 64-row step
    const int ldsOff = isK ? w8 * 1024 : (w8 - 4) * 1024;

    // swizzled read offsets (in shorts)
    const int kslot = ((l16 >> 1) & 3);     // K frag: (quad^kslot)*8
    const int vswz  = (l16 & 7);            // V frag: ((ks*4+quad)^vswz)*8

    // paired tiles: A = bx (short), B = 15-bx (long); NTA < NTB always
    const int NTA = 2 * bx + 2, NTB = 32 - 2 * bx;
    const int qbaseA = bx * 128 + w8 * 16;
    const int qbaseB = (15 - bx) * 128 + w8 * 16;

    bf16x8 qfA = *(const bf16x8*)(qn + ((size_t)bh * TT + qbaseA + l16) * RP + quad * 8);
    bf16x8 qfB = *(const bf16x8*)(qn + ((size_t)bh * TT + qbaseB + l16) * RP + quad * 8);

    float lsumA = 0.f, lsumB = 0.f;
    f32x4 oA0 = (f32x4){0.f, 0.f, 0.f, 0.f};
    f32x4 oA1 = (f32x4){0.f, 0.f, 0.f, 0.f};
    f32x4 oB0 = (f32x4){0.f, 0.f, 0.f, 0.f};
    f32x4 oB1 = (f32x4){0.f, 0.f, 0.f, 0.f};

    // prologue: stage step 0 into buffer 0
    gl2lds16(sBase, (isK ? (char*)KsF[0] : (char*)VsF[0]) + ldsOff);
    int cur = 0;

    for (int st = 0; st < NTB; ++st) {
        // wait my buf[cur] DMA (issued a full compute phase ago), then
        // barrier: all waves' DMAs landed AND prev compute closed.
        asm volatile("s_waitcnt vmcnt(0)\n\ts_barrier" ::: "memory");

        // issue next step's DMA into the alternate buffer (WAR closed by
        // barrier). Tail (st=NTB-1) reads dead-but-mapped workspace.
        const int nxt = cur ^ 1;
        gl2lds16(sBase + (long long)(st + 1) * sStep,
                 (isK ? (char*)KsF[nxt] : (char*)VsF[nxt]) + ldsOff);

        const int s0 = st * 64;
        const short* KsC = KsF[cur];
        const short* VsC = VsF[cur];

        ATTN_TILE(qfB, qbaseB, lsumB, oB0, oB1)
        if (st < NTA) {                        // block-uniform branch
            ATTN_TILE(qfA, qbaseA, lsumA, oA0, oA1)
        }
        cur = nxt;
    }

    ATTN_EPI(qbaseA, lsumA, oA0, oA1)
    ATTN_EPI(qbaseB, lsumB, oB0, oB1)
}

// ---------------------------------------------------------------------------
// Workspace (BYTE offsets from base = d_ws + 64):
//   xb    bf16 [0, 16777216)            (dead after gemm_k64)
//   wqT   bf16 [16777216, 18874368)     (dead after gemm_qrms; attn tail
//                                        prefetch may read here -> harmless)
//   wkvT  bf16 [18874368, 19136512)     (dead after gemm_k64)
//   kvb   bf16 [19136512, 21233664)     (dead after gemm_kv)
//   att_b bf16 [0, 8388608)             (alias over dead xb lower half)
//   vTb   bf16 [8388608, 16777216)      (alias over dead xb upper half;
//                                        written directly by gemm_kv)
//   qn    bf16 [35913728, 44302336)
//   kn    bf16 [44302336, 52690944)     (attn tail prefetch -> old vb region,
//                                        harmless: mapped workspace)
//   (old vb region [52690944, 61079552) now unused)
//   wkwvT bf16 [61079552, 61341696)
//   woT   bf16 [61341696, 62390272)
// ---------------------------------------------------------------------------
extern "C" void kernel_launch(void* const* d_in, const int* in_sizes, int n_in,
                              void* d_out, int out_size, void* d_ws, size_t ws_size,
                              hipStream_t stream)
{
    float* out = (float*)d_out;
    const long long NOUT = (long long)BB * TT * DD;
    const int outgrid = (int)((NOUT + 255) / 256);

    static const long long expect[8] =
        {8388608, 1048576, 131072, 65536, 65536, 1048576, 64, 32};
    if (n_in != 8) {
        sentinel_kernel<<<outgrid, 256, 0, stream>>>(out, 20000.0f + 100.0f * n_in, NOUT);
        return;
    }
    for (int i = 0; i < 8; ++i) {
        if ((long long)in_sizes[i] != expect[i]) {
            sentinel_kernel<<<outgrid, 256, 0, stream>>>(out, 10000.0f + 1000.0f * i, NOUT);
            return;
        }
    }
    if (ws_size < 62914624ULL) {
        sentinel_kernel<<<outgrid, 256, 0, stream>>>(
            out, 30000.0f + (float)(ws_size >> 20), NOUT);
        return;
    }
    if (out_size != 8388608) {
        sentinel_kernel<<<outgrid, 256, 0, stream>>>(
            out, 512.0f * (1.0f + (float)(out_size >> 20)), NOUT);
        return;
    }

    const float* x   = (const float*)d_in[0];
    const float* Wq  = (const float*)d_in[1];
    const float* Wkv = (const float*)d_in[2];
    const float* Wk  = (const float*)d_in[3];
    const float* Wv  = (const float*)d_in[4];
    const float* Wo  = (const float*)d_in[5];
    const float* qg  = (const float*)d_in[6];
    const float* kg  = (const float*)d_in[7];

    char* base = (char*)d_ws + 64;
    bf16*  xb    = (bf16*)(base + 0);
    bf16*  wqT   = (bf16*)(base + 16777216);
    bf16*  wkvT  = (bf16*)(base + 18874368);
    bf16*  kvb   = (bf16*)(base + 19136512);
    bf16*  att_b = (bf16*)(base + 0);
    bf16*  vTb   = (bf16*)(base + 8388608);
    bf16*  qn    = (bf16*)(base + 35913728);
    bf16*  kn    = (bf16*)(base + 44302336);
    bf16*  wkwvT = (bf16*)(base + 61079552);
    bf16*  woT   = (bf16*)(base + 61341696);

    const int BT = BB * TT;                    // 8192

    // 0. converts
    conv_x_kernel<<<outgrid / 4, 256, 0, stream>>>(x, xb, NOUT / 4);
    conv_trans_kernel<<<dim3(16, 16), 256, 0, stream>>>(Wq, wqT, 1024, 1024);
    conv_trans_kernel<<<dim3(2, 16), 256, 0, stream>>>(Wkv, wkvT, 1024, 128);
    conv_wkwv_kernel<<<512, 256, 0, stream>>>(Wk, Wv, wkwvT);
    conv_woT_kernel<<<dim3(16, 8), 256, 0, stream>>>(Wo, woT);

    // 1. qn = rmsnorm(xb @ Wq)[:, :32] * 0.125*log2e (fused epilogue)
    gemm_qrms<<<dim3(8, 64), 256, 0, stream>>>(
        (const short*)xb, (const short*)wqT, qn, qg, BT, DD, DD);
    // 2. kvb = xb @ Wkv (64-row tiles -> 128 blocks), 8192x128, K=1024
    gemm_k64<<<dim3(1, 128), 256, 0, stream>>>(
        (const short*)xb, (const short*)wkvT, kvb, BT, LAT_, DD);
    // 3. kn / vT = fused(kvb @ [Wk|Wv]) (K-RMS + transposed V write)
    gemm_kv<<<dim3(8, 64), 256, 0, stream>>>(
        (const short*)kvb, (const short*)wkwvT, kn, vTb, kg, BT, 2 * 512, LAT_);
    // 4. flash MFMA attention (paired-tile sweep, dbuf staging, exp2)
    attn_mfma<<<dim3(8, 64), 512, 0, stream>>>(qn, kn, vTb, att_b);
    // 5. out = att_b @ Wo_remap (MFMA), 8192x1024, K=512
    gemm_mfma<float><<<dim3(8, 64), 256, 0, stream>>>(
        (const short*)att_b, (const short*)woT, out, BT, DD, 512);
}

// Round 15
// 227.109 us; speedup vs baseline: 1.0499x; 1.0499x over previous
//
#include <hip/hip_runtime.h>
#include <hip/hip_bf16.h>
#include <math.h>

using bf16 = __hip_bfloat16;
typedef __attribute__((ext_vector_type(8))) short bf16x8;
typedef __attribute__((ext_vector_type(4))) float f32x4;

#define BB   4
#define TT   2048
#define DD   1024
#define HH   16
#define HD_  64
#define LAT_ 128
#define RP   32
#define EPS_ 1e-6f
// 1/sqrt(64): folded into qn; attn uses __expf (fast: v_mul+v_exp)
#define QSCALE_ 0.125f

static __device__ __forceinline__ void stf(float* p, float v) { *p = v; }
static __device__ __forceinline__ void stf(bf16* p, float v) { *p = __float2bfloat16(v); }

// global -> LDS 16B DMA (wave-uniform LDS base + lane*16)
static __device__ __forceinline__ void gl2lds16(const void* g, void* l)
{
    __builtin_amdgcn_global_load_lds(
        (const __attribute__((address_space(1))) void*)g,
        (__attribute__((address_space(3))) void*)l, 16, 0, 0);
}

__global__ __launch_bounds__(256)
void sentinel_kernel(float* __restrict__ out, float val, long long n)
{
    long long i = (long long)blockIdx.x * 256 + threadIdx.x;
    if (i < n) out[i] = val;
}

// ---------------------------------------------------------------------------
// Converters
// ---------------------------------------------------------------------------
__global__ __launch_bounds__(256)
void conv_x_kernel(const float* __restrict__ x, bf16* __restrict__ xb, long long n4)
{
    long long i = (long long)blockIdx.x * 256 + threadIdx.x;
    if (i >= n4) return;
    float4 v = *(const float4*)(x + i * 4);
    union { bf16 h[4]; uint2 u; } o;
    o.h[0] = __float2bfloat16(v.x);
    o.h[1] = __float2bfloat16(v.y);
    o.h[2] = __float2bfloat16(v.z);
    o.h[3] = __float2bfloat16(v.w);
    *(uint2*)(xb + i * 4) = o.u;
}

// Tiled transpose-convert: W (K x N fp32 row-major) -> WT (N x K bf16).
__global__ __launch_bounds__(256)
void conv_trans_kernel(const float* __restrict__ W, bf16* __restrict__ WT,
                       int K, int N)
{
    __shared__ __align__(16) bf16 t[64][72];
    const int k0 = blockIdx.y * 64, n0 = blockIdx.x * 64;
    const int tid = threadIdx.x;
    const int r = tid >> 2, c0 = (tid & 3) * 16;
    const float* src = W + (size_t)(k0 + r) * N + n0 + c0;
    #pragma unroll
    for (int j = 0; j < 16; j += 4) {
        float4 v = *(const float4*)(src + j);
        t[c0 + j + 0][r] = __float2bfloat16(v.x);
        t[c0 + j + 1][r] = __float2bfloat16(v.y);
        t[c0 + j + 2][r] = __float2bfloat16(v.z);
        t[c0 + j + 3][r] = __float2bfloat16(v.w);
    }
    __syncthreads();
    const int rr = tid >> 2, cc = (tid & 3) * 16;
    bf16* dst = WT + (size_t)(n0 + rr) * K + k0 + cc;
    *(bf16x8*)dst       = *(const bf16x8*)&t[rr][cc];
    *(bf16x8*)(dst + 8) = *(const bf16x8*)&t[rr][cc + 8];
}

// [Wk | Wv] (each 128x512) -> WT (1024 x 128).
__global__ __launch_bounds__(256)
void conv_wkwv_kernel(const float* __restrict__ Wk, const float* __restrict__ Wv,
                      bf16* __restrict__ WT)
{
    int idx = blockIdx.x * 256 + threadIdx.x;      // 128*1024
    if (idx >= 128 * 1024) return;
    int k = idx >> 10, n = idx & 1023;
    float v = (n < 512) ? Wk[k * 512 + n] : Wv[k * 512 + (n - 512)];
    WT[(size_t)n * 128 + k] = __float2bfloat16(v);
}

// Wo (1024x1024) -> woT (1024 x 512) tiled transpose with row remap.
__global__ __launch_bounds__(256)
void conv_woT_kernel(const float* __restrict__ Wo, bf16* __restrict__ WT)
{
    __shared__ __align__(16) bf16 t[64][72];
    const int mm0 = blockIdx.y * 64, n0 = blockIdx.x * 64;
    const int tid = threadIdx.x;
    const int r = tid >> 2, c0 = (tid & 3) * 16;
    const int mm = mm0 + r;
    const int row = ((mm >> 5) << 6) | (mm & 31);
    const float* src = Wo + (size_t)row * 1024 + n0 + c0;
    #pragma unroll
    for (int j = 0; j < 16; j += 4) {
        float4 v = *(const float4*)(src + j);
        t[c0 + j + 0][r] = __float2bfloat16(v.x);
        t[c0 + j + 1][r] = __float2bfloat16(v.y);
        t[c0 + j + 2][r] = __float2bfloat16(v.z);
        t[c0 + j + 3][r] = __float2bfloat16(v.w);
    }
    __syncthreads();
    const int rr = tid >> 2, cc = (tid & 3) * 16;
    bf16* dst = WT + (size_t)(n0 + rr) * 512 + mm0 + cc;
    *(bf16x8*)dst       = *(const bf16x8*)&t[rr][cc];
    *(bf16x8*)(dst + 8) = *(const bf16x8*)&t[rr][cc + 8];
}

// ---------------------------------------------------------------------------
// MFMA GEMM with global_load_lds staging. C[M,N] = A @ B, A bf16 (M x K)
// row-major, BT bf16 (N x K) row-major. 128x128 tile, BK=32.
// Fragment maps (HW-verified): A[m=lane&15][k=quad*8+j],
// BT[n=lane&15][k=quad*8+j], C/D row=quad*4+reg, col=lane&15.
// ---------------------------------------------------------------------------
#define GEMM_PROLOG_128 \
    __shared__ __align__(16) short As[128][32]; \
    __shared__ __align__(16) short Bs[128][32]; \
    const int tid  = threadIdx.x; \
    const int wave = tid >> 6, lane = tid & 63; \
    const int quad = lane >> 4, l16 = lane & 15; \
    const int wr = (wave >> 1) * 64, wc = (wave & 1) * 64; \
    const int row0 = blockIdx.y * 128, col0 = blockIdx.x * 128; \
    const int srow = tid >> 2, scol = (tid & 3) * 8; \
    char* lAs0 = (char*)As + wave * 1024; \
    char* lAs1 = (char*)As + 4096 + wave * 1024; \
    char* lBs0 = (char*)Bs + wave * 1024; \
    char* lBs1 = (char*)Bs + 4096 + wave * 1024; \
    f32x4 acc[4][4]; \
    _Pragma("unroll") \
    for (int mt = 0; mt < 4; ++mt) \
        _Pragma("unroll") \
        for (int nt = 0; nt < 4; ++nt) \
            acc[mt][nt] = (f32x4){0.f, 0.f, 0.f, 0.f}; \
    for (int k0 = 0; k0 < K; k0 += 32) { \
        const short* ga = A  + (size_t)(row0 + srow) * K + k0 + scol; \
        const short* gb = BT + (size_t)(col0 + srow) * K + k0 + scol; \
        __syncthreads(); \
        gl2lds16(ga,                  lAs0); \
        gl2lds16(ga + (size_t)64 * K, lAs1); \
        gl2lds16(gb,                  lBs0); \
        gl2lds16(gb + (size_t)64 * K, lBs1); \
        __syncthreads(); \
        bf16x8 af[4], bfv[4]; \
        _Pragma("unroll") \
        for (int mt = 0; mt < 4; ++mt) \
            af[mt] = *(const bf16x8*)&As[wr + mt * 16 + l16][quad * 8]; \
        _Pragma("unroll") \
        for (int nt = 0; nt < 4; ++nt) \
            bfv[nt] = *(const bf16x8*)&Bs[wc + nt * 16 + l16][quad * 8]; \
        _Pragma("unroll") \
        for (int mt = 0; mt < 4; ++mt) \
            _Pragma("unroll") \
            for (int nt = 0; nt < 4; ++nt) \
                acc[mt][nt] = __builtin_amdgcn_mfma_f32_16x16x32_bf16( \
                    af[mt], bfv[nt], acc[mt][nt], 0, 0, 0); \
    }

template <typename OT>
__global__ __launch_bounds__(256)
void gemm_mfma(const short* __restrict__ A, const short* __restrict__ BT,
               OT* __restrict__ C, int M, int N, int K)
{
    GEMM_PROLOG_128
    #pragma unroll
    for (int mt = 0; mt < 4; ++mt)
        #pragma unroll
        for (int nt = 0; nt < 4; ++nt) {
            const int col = col0 + wc + nt * 16 + l16;
            #pragma unroll
            for (int r = 0; r < 4; ++r) {
                const int row = row0 + wr + mt * 16 + quad * 4 + r;
                stf(C + (size_t)row * N + col, acc[mt][nt][r]);
            }
        }
}

// ---------------------------------------------------------------------------
// GEMM1 + fused Q-RMSNorm epilogue. qn pre-scaled by 1/sqrt(64).
// ---------------------------------------------------------------------------
__global__ __launch_bounds__(256)
void gemm_qrms(const short* __restrict__ A, const short* __restrict__ BT,
               bf16* __restrict__ qn, const float* __restrict__ qg,
               int M, int N, int K)
{
    GEMM_PROLOG_128
    const int h = (col0 + wc) >> 6;
    const float g0 = qg[l16], g1 = qg[16 + l16];
    #pragma unroll
    for (int mt = 0; mt < 4; ++mt) {
        float ss[4];
        #pragma unroll
        for (int r = 0; r < 4; ++r)
            ss[r] = acc[mt][0][r] * acc[mt][0][r] + acc[mt][1][r] * acc[mt][1][r]
                  + acc[mt][2][r] * acc[mt][2][r] + acc[mt][3][r] * acc[mt][3][r];
        #pragma unroll
        for (int off = 1; off < 16; off <<= 1)
            #pragma unroll
            for (int r = 0; r < 4; ++r) ss[r] += __shfl_xor(ss[r], off, 64);
        #pragma unroll
        for (int r = 0; r < 4; ++r) {
            const float inv = QSCALE_ / sqrtf(ss[r] * (1.0f / HD_) + EPS_);
            const int row = row0 + wr + mt * 16 + quad * 4 + r;
            const int b = row >> 11, t = row & 2047;
            bf16* op = qn + (((size_t)(b * HH + h)) * TT + t) * RP;
            op[l16]      = __float2bfloat16(g0 * acc[mt][0][r] * inv);
            op[16 + l16] = __float2bfloat16(g1 * acc[mt][1][r] * inv);
        }
    }
}

// ---------------------------------------------------------------------------
// GEMM4 + fused K-RMSNorm / V-split epilogue. V path writes vT (bh,32,2048)
// DIRECTLY (transposed), eliminating the vtrans kernel.
// ---------------------------------------------------------------------------
struct __attribute__((aligned(8))) bf4 { bf16 v[4]; };

__global__ __launch_bounds__(256)
void gemm_kv(const short* __restrict__ A, const short* __restrict__ BT,
             bf16* __restrict__ kn, bf16* __restrict__ vT,
             const float* __restrict__ kg, int M, int N, int K)
{
    GEMM_PROLOG_128
    const int colbase = col0 + wc;
    if (colbase < 512) {                        // K-RMS path
        const int h0 = colbase >> 5;            // groups h0, h0+1
        const float g0 = kg[l16], g1 = kg[16 + l16];
        #pragma unroll
        for (int mt = 0; mt < 4; ++mt) {
            float s0[4], s1[4];
            #pragma unroll
            for (int r = 0; r < 4; ++r) {
                s0[r] = acc[mt][0][r] * acc[mt][0][r] + acc[mt][1][r] * acc[mt][1][r];
                s1[r] = acc[mt][2][r] * acc[mt][2][r] + acc[mt][3][r] * acc[mt][3][r];
            }
            #pragma unroll
            for (int off = 1; off < 16; off <<= 1)
                #pragma unroll
                for (int r = 0; r < 4; ++r) {
                    s0[r] += __shfl_xor(s0[r], off, 64);
                    s1[r] += __shfl_xor(s1[r], off, 64);
                }
            #pragma unroll
            for (int r = 0; r < 4; ++r) {
                const float i0 = 1.0f / sqrtf(s0[r] * (1.0f / RP) + EPS_);
                const float i1 = 1.0f / sqrtf(s1[r] * (1.0f / RP) + EPS_);
                const int row = row0 + wr + mt * 16 + quad * 4 + r;
                const int b = row >> 11, t = row & 2047;
                bf16* op0 = kn + (((size_t)(b * HH + h0)) * TT + t) * RP;
                bf16* op1 = kn + (((size_t)(b * HH + h0 + 1)) * TT + t) * RP;
                op0[l16]      = __float2bfloat16(g0 * acc[mt][0][r] * i0);
                op0[16 + l16] = __float2bfloat16(g1 * acc[mt][1][r] * i0);
                op1[l16]      = __float2bfloat16(g0 * acc[mt][2][r] * i1);
                op1[16 + l16] = __float2bfloat16(g1 * acc[mt][3][r] * i1);
            }
        }
    } else {                                     // V path -> transposed vT
        const int h0 = (colbase - 512) >> 5;
        #pragma unroll
        for (int mt = 0; mt < 4; ++mt)
            #pragma unroll
            for (int nt = 0; nt < 4; ++nt) {
                const int h = h0 + (nt >> 1);
                const int c = (nt & 1) * 16 + l16;
                const int row = row0 + wr + mt * 16 + quad * 4;   // r=0 base
                const int b = row >> 11, t = row & 2047;
                bf4 pk;
                #pragma unroll
                for (int r = 0; r < 4; ++r)
                    pk.v[r] = __float2bfloat16(acc[mt][nt][r]);
                *(bf4*)(vT + (((size_t)(b * HH + h)) * RP + c) * TT + t) = pk;
            }
    }
}

// ---------------------------------------------------------------------------
// 64x128-tile GEMM (gemm3: 8192x128, K=1024 -> 128 blocks).
// ---------------------------------------------------------------------------
__global__ __launch_bounds__(256)
void gemm_k64(const short* __restrict__ A, const short* __restrict__ BT,
              bf16* __restrict__ C, int M, int N, int K)
{
    __shared__ __align__(16) short As[64][32];
    __shared__ __align__(16) short Bs[128][32];
    const int tid  = threadIdx.x;
    const int wave = tid >> 6, lane = tid & 63;
    const int quad = lane >> 4, l16 = lane & 15;
    const int wr = (wave >> 1) * 32, wc = (wave & 1) * 64;
    const int row0 = blockIdx.y * 64, col0 = blockIdx.x * 128;
    const int srow = tid >> 2, scol = (tid & 3) * 8;

    char* lAs  = (char*)As + wave * 1024;
    char* lBs0 = (char*)Bs + wave * 1024;
    char* lBs1 = (char*)Bs + 4096 + wave * 1024;

    f32x4 acc[2][4];
    #pragma unroll
    for (int mt = 0; mt < 2; ++mt)
        #pragma unroll
        for (int nt = 0; nt < 4; ++nt)
            acc[mt][nt] = (f32x4){0.f, 0.f, 0.f, 0.f};

    for (int k0 = 0; k0 < K; k0 += 32) {
        const short* ga = A  + (size_t)(row0 + srow) * K + k0 + scol;
        const short* gb = BT + (size_t)(col0 + srow) * K + k0 + scol;
        __syncthreads();
        gl2lds16(ga,                  lAs);
        gl2lds16(gb,                  lBs0);
        gl2lds16(gb + (size_t)64 * K, lBs1);
        __syncthreads();

        bf16x8 af[2], bfv[4];
        #pragma unroll
        for (int mt = 0; mt < 2; ++mt)
            af[mt] = *(const bf16x8*)&As[wr + mt * 16 + l16][quad * 8];
        #pragma unroll
        for (int nt = 0; nt < 4; ++nt)
            bfv[nt] = *(const bf16x8*)&Bs[wc + nt * 16 + l16][quad * 8];
        #pragma unroll
        for (int mt = 0; mt < 2; ++mt)
            #pragma unroll
            for (int nt = 0; nt < 4; ++nt)
                acc[mt][nt] = __builtin_amdgcn_mfma_f32_16x16x32_bf16(
                    af[mt], bfv[nt], acc[mt][nt], 0, 0, 0);
    }

    #pragma unroll
    for (int mt = 0; mt < 2; ++mt)
        #pragma unroll
        for (int nt = 0; nt < 4; ++nt) {
            const int col = col0 + wc + nt * 16 + l16;
            #pragma unroll
            for (int r = 0; r < 4; ++r) {
                const int row = row0 + wr + mt * 16 + quad * 4 + r;
                C[(size_t)row * N + col] = __float2bfloat16(acc[mt][nt][r]);
            }
        }
}

// ---------------------------------------------------------------------------
// Flash MFMA attention v9 = paired-tile single sweep, dbuf staging, XOR
// swizzle, fast __expf (qn pre-scaled by 0.125 only).
// ---------------------------------------------------------------------------
#define ATTN_TILE(QF, QB, LSUM, OA, OB)                                         \
    {                                                                           \
        f32x4 sc[4];                                                            \
        _Pragma("unroll")                                                       \
        for (int sub = 0; sub < 4; ++sub) {                                     \
            bf16x8 kf = *(const bf16x8*)&KsC[(sub * 16 + l16) * 32              \
                                             + ((quad ^ kslot) * 8)];           \
            sc[sub] = __builtin_amdgcn_mfma_f32_16x16x32_bf16(                  \
                kf, QF, (f32x4){0.f, 0.f, 0.f, 0.f}, 0, 0, 0);                  \
        }                                                                       \
        if (s0 + 63 > (QB)) {                                                   \
            const int qg_ = (QB) + l16;                                         \
            _Pragma("unroll")                                                   \
            for (int sub = 0; sub < 4; ++sub)                                   \
                _Pragma("unroll")                                               \
                for (int r = 0; r < 4; ++r)                                     \
                    if (s0 + sub * 16 + quad * 4 + r > qg_) sc[sub][r] = -1e30f;\
        }                                                                       \
        _Pragma("unroll")                                                       \
        for (int sub = 0; sub < 4; ++sub) {                                     \
            const float p0 = __expf(sc[sub][0]);                                \
            const float p1 = __expf(sc[sub][1]);                                \
            const float p2 = __expf(sc[sub][2]);                                \
            const float p3 = __expf(sc[sub][3]);                                \
            bf4 pk;                                                             \
            pk.v[0] = __float2bfloat16(p0);                                     \
            pk.v[1] = __float2bfloat16(p1);                                     \
            pk.v[2] = __float2bfloat16(p2);                                     \
            pk.v[3] = __float2bfloat16(p3);                                     \
            *(bf4*)&P_lds[w8][l16][sub * 16 + quad * 4] = pk;                   \
            LSUM += (p0 + p1) + (p2 + p3);                                      \
        }                                                                       \
        _Pragma("unroll")                                                       \
        for (int ks = 0; ks < 2; ++ks) {                                        \
            bf16x8 pf  = *(const bf16x8*)&P_lds[w8][l16][ks * 32 + quad * 8];   \
            bf16x8 vf0 = *(const bf16x8*)&VsC[l16 * 64                          \
                            + (((ks * 4 + quad) ^ vswz) * 8)];                  \
            bf16x8 vf1 = *(const bf16x8*)&VsC[(16 + l16) * 64                   \
                            + (((ks * 4 + quad) ^ vswz) * 8)];                  \
            OA = __builtin_amdgcn_mfma_f32_16x16x32_bf16(pf, vf0, OA, 0, 0, 0); \
            OB = __builtin_amdgcn_mfma_f32_16x16x32_bf16(pf, vf1, OB, 0, 0, 0); \
        }                                                                       \
    }

#define ATTN_EPI(QB, LSUM, OA, OB)                                              \
    {                                                                           \
        float ls_ = (LSUM);                                                     \
        ls_ += __shfl_xor(ls_, 16, 64);                                         \
        ls_ += __shfl_xor(ls_, 32, 64);                                         \
        _Pragma("unroll")                                                       \
        for (int r = 0; r < 4; ++r) {                                           \
            const float lr  = __shfl(ls_, quad * 20 + r, 64);                   \
            const float inv = 1.0f / lr;                                        \
            const int t = (QB) + quad * 4 + r;                                  \
            bf16* op = att + ((size_t)(b * TT + t)) * 512 + h * 32;             \
            op[l16]      = __float2bfloat16((OA)[r] * inv);                     \
            op[16 + l16] = __float2bfloat16((OB)[r] * inv);                     \
        }                                                                       \
    }

__global__ __launch_bounds__(512, 4)
void attn_mfma(const bf16* __restrict__ qn, const bf16* __restrict__ kn,
               const bf16* __restrict__ vT, bf16* __restrict__ att)
{
    __shared__ __align__(16) short KsF[2][64 * 32];   // 8 KB, swizzled slots
    __shared__ __align__(16) short VsF[2][32 * 64];   // 8 KB, swizzled slots
    __shared__ __align__(16) bf16 P_lds[8][16][72];   // 18 KB
    const int tid  = threadIdx.x;
    const int w8   = tid >> 6, lane = tid & 63;
    const int quad = lane >> 4, l16 = lane & 15;
    // XCD-aware bijective remap: f -> (bx 0..7, bh 0..63), bh%8 == xcd
    const int f  = (int)(blockIdx.y * 8 + blockIdx.x);     // 0..511
    const int xr = f & 7, j = f >> 3;                       // j: 0..63
    const int bx = j & 7;
    const int bh = xr + 8 * (j >> 3);
    const int b = bh >> 4, h = bh & 15;

    const bf16* knb = kn + (size_t)bh * TT * RP;
    const bf16* vtb = vT + (size_t)bh * RP * TT;

    // staging map (LDS dest linear within buffer; source pre-swizzled):
    // K chunk c (=tid, waves 0-3): row=c>>2, gslot=(c&3)^((c>>3)&3)
    // V chunk c (=tid-256, waves 4-7): row=c>>3, gslot=(c&7)^((c>>3)&7)
    const bool isK = (w8 < 4);
    const int  cK = tid;
    const int  cV = tid - 256;
    const bf16* sBase = isK
        ? knb + (size_t)(cK >> 2) * RP + ((cK & 3) ^ ((cK >> 3) & 3)) * 8
        : vtb + (size_t)(cV >> 3) * TT + ((cV & 7) ^ ((cV >> 3) & 7)) * 8;
    const long long sStep = (long long)(isK ? RP : 1) * 64;  // per 64-row step
    const int ldsOff = isK ? w8 * 1024 : (w8 - 4) * 1024;

    // swizzled read offsets (in shorts)
    const int kslot = ((l16 >> 1) & 3);     // K frag: (quad^kslot)*8
    const int vswz  = (l16 & 7);            // V frag: ((ks*4+quad)^vswz)*8

    // paired tiles: A = bx (short), B = 15-bx (long); NTA < NTB always
    const int NTA = 2 * bx + 2, NTB = 32 - 2 * bx;
    const int qbaseA = bx * 128 + w8 * 16;
    const int qbaseB = (15 - bx) * 128 + w8 * 16;

    bf16x8 qfA = *(const bf16x8*)(qn + ((size_t)bh * TT + qbaseA + l16) * RP + quad * 8);
    bf16x8 qfB = *(const bf16x8*)(qn + ((size_t)bh * TT + qbaseB + l16) * RP + quad * 8);

    float lsumA = 0.f, lsumB = 0.f;
    f32x4 oA0 = (f32x4){0.f, 0.f, 0.f, 0.f};
    f32x4 oA1 = (f32x4){0.f, 0.f, 0.f, 0.f};
    f32x4 oB0 = (f32x4){0.f, 0.f, 0.f, 0.f};
    f32x4 oB1 = (f32x4){0.f, 0.f, 0.f, 0.f};

    // prologue: stage step 0 into buffer 0
    gl2lds16(sBase, (isK ? (char*)KsF[0] : (char*)VsF[0]) + ldsOff);
    int cur = 0;

    for (int st = 0; st < NTB; ++st) {
        // wait my buf[cur] DMA (issued a full compute phase ago), then
        // barrier: all waves' DMAs landed AND prev compute closed.
        asm volatile("s_waitcnt vmcnt(0)\n\ts_barrier" ::: "memory");

        // issue next step's DMA into the alternate buffer (WAR closed by
        // barrier). Tail (st=NTB-1) reads dead-but-mapped workspace.
        const int nxt = cur ^ 1;
        gl2lds16(sBase + (long long)(st + 1) * sStep,
                 (isK ? (char*)KsF[nxt] : (char*)VsF[nxt]) + ldsOff);

        const int s0 = st * 64;
        const short* KsC = KsF[cur];
        const short* VsC = VsF[cur];

        ATTN_TILE(qfB, qbaseB, lsumB, oB0, oB1)
        if (st < NTA) {                        // block-uniform branch
            ATTN_TILE(qfA, qbaseA, lsumA, oA0, oA1)
        }
        cur = nxt;
    }

    ATTN_EPI(qbaseA, lsumA, oA0, oA1)
    ATTN_EPI(qbaseB, lsumB, oB0, oB1)
}

// ---------------------------------------------------------------------------
// Workspace (BYTE offsets from base = d_ws + 64):
//   xb    bf16 [0, 16777216)            (dead after gemm_k64)
//   wqT   bf16 [16777216, 18874368)     (dead after gemm_qrms)
//   wkvT  bf16 [18874368, 19136512)     (dead after gemm_k64)
//   kvb   bf16 [19136512, 21233664)     (dead after gemm_kv)
//   att_b bf16 [0, 8388608)             (alias over dead xb lower half)
//   vTb   bf16 [8388608, 16777216)      (alias over dead xb upper half;
//                                        written directly by gemm_kv)
//   qn    bf16 [35913728, 44302336)
//   kn    bf16 [44302336, 52690944)     (attn tail prefetch -> old vb region,
//                                        harmless: mapped workspace)
//   (old vb region [52690944, 61079552) unused)
//   wkwvT bf16 [61079552, 61341696)
//   woT   bf16 [61341696, 62390272)
// ---------------------------------------------------------------------------
extern "C" void kernel_launch(void* const* d_in, const int* in_sizes, int n_in,
                              void* d_out, int out_size, void* d_ws, size_t ws_size,
                              hipStream_t stream)
{
    float* out = (float*)d_out;
    const long long NOUT = (long long)BB * TT * DD;
    const int outgrid = (int)((NOUT + 255) / 256);

    static const long long expect[8] =
        {8388608, 1048576, 131072, 65536, 65536, 1048576, 64, 32};
    if (n_in != 8) {
        sentinel_kernel<<<outgrid, 256, 0, stream>>>(out, 20000.0f + 100.0f * n_in, NOUT);
        return;
    }
    for (int i = 0; i < 8; ++i) {
        if ((long long)in_sizes[i] != expect[i]) {
            sentinel_kernel<<<outgrid, 256, 0, stream>>>(out, 10000.0f + 1000.0f * i, NOUT);
            return;
        }
    }
    if (ws_size < 62914624ULL) {
        sentinel_kernel<<<outgrid, 256, 0, stream>>>(
            out, 30000.0f + (float)(ws_size >> 20), NOUT);
        return;
    }
    if (out_size != 8388608) {
        sentinel_kernel<<<outgrid, 256, 0, stream>>>(
            out, 512.0f * (1.0f + (float)(out_size >> 20)), NOUT);
        return;
    }

    const float* x   = (const float*)d_in[0];
    const float* Wq  = (const float*)d_in[1];
    const float* Wkv = (const float*)d_in[2];
    const float* Wk  = (const float*)d_in[3];
    const float* Wv  = (const float*)d_in[4];
    const float* Wo  = (const float*)d_in[5];
    const float* qg  = (const float*)d_in[6];
    const float* kg  = (const float*)d_in[7];

    char* base = (char*)d_ws + 64;
    bf16*  xb    = (bf16*)(base + 0);
    bf16*  wqT   = (bf16*)(base + 16777216);
    bf16*  wkvT  = (bf16*)(base + 18874368);
    bf16*  kvb   = (bf16*)(base + 19136512);
    bf16*  att_b = (bf16*)(base + 0);
    bf16*  vTb   = (bf16*)(base + 8388608);
    bf16*  qn    = (bf16*)(base + 35913728);
    bf16*  kn    = (bf16*)(base + 44302336);
    bf16*  wkwvT = (bf16*)(base + 61079552);
    bf16*  woT   = (bf16*)(base + 61341696);

    const int BT = BB * TT;                    // 8192

    // 0. converts
    conv_x_kernel<<<outgrid / 4, 256, 0, stream>>>(x, xb, NOUT / 4);
    conv_trans_kernel<<<dim3(16, 16), 256, 0, stream>>>(Wq, wqT, 1024, 1024);
    conv_trans_kernel<<<dim3(2, 16), 256, 0, stream>>>(Wkv, wkvT, 1024, 128);
    conv_wkwv_kernel<<<512, 256, 0, stream>>>(Wk, Wv, wkwvT);
    conv_woT_kernel<<<dim3(16, 8), 256, 0, stream>>>(Wo, woT);

    // 1. qn = rmsnorm(xb @ Wq)[:, :32] * 0.125 (fused epilogue)
    gemm_qrms<<<dim3(8, 64), 256, 0, stream>>>(
        (const short*)xb, (const short*)wqT, qn, qg, BT, DD, DD);
    // 2. kvb = xb @ Wkv (64-row tiles -> 128 blocks), 8192x128, K=1024
    gemm_k64<<<dim3(1, 128), 256, 0, stream>>>(
        (const short*)xb, (const short*)wkvT, kvb, BT, LAT_, DD);
    // 3. kn / vT = fused(kvb @ [Wk|Wv]) (K-RMS + transposed V write)
    gemm_kv<<<dim3(8, 64), 256, 0, stream>>>(
        (const short*)kvb, (const short*)wkwvT, kn, vTb, kg, BT, 2 * 512, LAT_);
    // 4. flash MFMA attention (paired-tile sweep, dbuf staging, __expf)
    attn_mfma<<<dim3(8, 64), 512, 0, stream>>>(qn, kn, vTb, att_b);
    // 5. out = att_b @ Wo_remap (MFMA), 8192x1024, K=512
    gemm_mfma<float><<<dim3(8, 64), 256, 0, stream>>>(
        (const short*)att_b, (const short*)woT, out, BT, DD, 512);
}

// Round 16
// 203.201 us; speedup vs baseline: 1.1734x; 1.1177x over previous
//
#include <hip/hip_runtime.h>
#include <hip/hip_bf16.h>
#include <math.h>

using bf16 = __hip_bfloat16;
typedef __attribute__((ext_vector_type(8))) short bf16x8;
typedef __attribute__((ext_vector_type(4))) float f32x4;

#define BB   4
#define TT   2048
#define DD   1024
#define HH   16
#define HD_  64
#define LAT_ 128
#define RP   32
#define EPS_ 1e-6f
#define QSCALE_ 0.125f

static __device__ __forceinline__ void stf(float* p, float v) { *p = v; }
static __device__ __forceinline__ void stf(bf16* p, float v) { *p = __float2bfloat16(v); }

// global -> LDS 16B DMA (wave-uniform LDS base + lane*16)
static __device__ __forceinline__ void gl2lds16(const void* g, void* l)
{
    __builtin_amdgcn_global_load_lds(
        (const __attribute__((address_space(1))) void*)g,
        (__attribute__((address_space(3))) void*)l, 16, 0, 0);
}

__global__ __launch_bounds__(256)
void sentinel_kernel(float* __restrict__ out, float val, long long n)
{
    long long i = (long long)blockIdx.x * 256 + threadIdx.x;
    if (i < n) out[i] = val;
}

// ---------------------------------------------------------------------------
// conv_all: ALL input conversions in ONE dispatch (flat-id partition).
//   [0, 8192)      conv_x: fp32 -> bf16, 1024 elems/block (float4 in)
//   [8192, 8448)   Wq transpose-convert (1024x1024): 256 tile-blocks
//   [8448, 8480)   Wkv transpose-convert (1024x128): 32 tile-blocks
//   [8480, 8992)   [Wk|Wv] -> wkwvT (1024x128): 512 blocks
//   [8992, 9120)   Wo -> woT (1024x512, row remap): 128 tile-blocks
// ---------------------------------------------------------------------------
__global__ __launch_bounds__(256)
void conv_all(const float* __restrict__ x,  bf16* __restrict__ xb,
              const float* __restrict__ Wq, bf16* __restrict__ wqT,
              const float* __restrict__ Wkv, bf16* __restrict__ wkvT,
              const float* __restrict__ Wk, const float* __restrict__ Wv,
              bf16* __restrict__ wkwvT,
              const float* __restrict__ Wo, bf16* __restrict__ woT)
{
    __shared__ __align__(16) bf16 t[64][72];
    const int bid = blockIdx.x;
    const int tid = threadIdx.x;

    if (bid < 8192) {                          // ---- conv_x ----
        const long long i = (long long)bid * 256 + tid;   // x4 elems
        float4 v = *(const float4*)(x + i * 4);
        union { bf16 h[4]; uint2 u; } o;
        o.h[0] = __float2bfloat16(v.x);
        o.h[1] = __float2bfloat16(v.y);
        o.h[2] = __float2bfloat16(v.z);
        o.h[3] = __float2bfloat16(v.w);
        *(uint2*)(xb + i * 4) = o.u;
        return;
    }
    if (bid < 8480) {                          // ---- transpose-convert ----
        const float* W; bf16* WT; int K, N, bx, by;
        if (bid < 8448) { W = Wq;  WT = wqT;  K = 1024; N = 1024;
                          bx = (bid - 8192) & 15; by = (bid - 8192) >> 4; }
        else            { W = Wkv; WT = wkvT; K = 1024; N = 128;
                          bx = (bid - 8448) & 1;  by = (bid - 8448) >> 1; }
        const int k0 = by * 64, n0 = bx * 64;
        const int r = tid >> 2, c0 = (tid & 3) * 16;
        const float* src = W + (size_t)(k0 + r) * N + n0 + c0;
        #pragma unroll
        for (int j = 0; j < 16; j += 4) {
            float4 v = *(const float4*)(src + j);
            t[c0 + j + 0][r] = __float2bfloat16(v.x);
            t[c0 + j + 1][r] = __float2bfloat16(v.y);
            t[c0 + j + 2][r] = __float2bfloat16(v.z);
            t[c0 + j + 3][r] = __float2bfloat16(v.w);
        }
        __syncthreads();
        const int rr = tid >> 2, cc = (tid & 3) * 16;
        bf16* dst = WT + (size_t)(n0 + rr) * K + k0 + cc;
        *(bf16x8*)dst       = *(const bf16x8*)&t[rr][cc];
        *(bf16x8*)(dst + 8) = *(const bf16x8*)&t[rr][cc + 8];
        return;
    }
    if (bid < 8992) {                          // ---- [Wk|Wv] -> wkwvT ----
        int idx = (bid - 8480) * 256 + tid;    // 128*1024
        int k = idx >> 10, n = idx & 1023;
        float v = (n < 512) ? Wk[k * 512 + n] : Wv[k * 512 + (n - 512)];
        wkwvT[(size_t)n * 128 + k] = __float2bfloat16(v);
        return;
    }
    {                                          // ---- Wo -> woT (remap) ----
        const int id = bid - 8992;             // grid (16 n-tiles, 8 mm-tiles)
        const int bx = id & 15, by = id >> 4;
        const int mm0 = by * 64, n0 = bx * 64;
        const int r = tid >> 2, c0 = (tid & 3) * 16;
        const int mm = mm0 + r;
        const int row = ((mm >> 5) << 6) | (mm & 31);
        const float* src = Wo + (size_t)row * 1024 + n0 + c0;
        #pragma unroll
        for (int j = 0; j < 16; j += 4) {
            float4 v = *(const float4*)(src + j);
            t[c0 + j + 0][r] = __float2bfloat16(v.x);
            t[c0 + j + 1][r] = __float2bfloat16(v.y);
            t[c0 + j + 2][r] = __float2bfloat16(v.z);
            t[c0 + j + 3][r] = __float2bfloat16(v.w);
        }
        __syncthreads();
        const int rr = tid >> 2, cc = (tid & 3) * 16;
        bf16* dst = woT + (size_t)(n0 + rr) * 512 + mm0 + cc;
        *(bf16x8*)dst       = *(const bf16x8*)&t[rr][cc];
        *(bf16x8*)(dst + 8) = *(const bf16x8*)&t[rr][cc + 8];
    }
}

// ---------------------------------------------------------------------------
// MFMA GEMM prolog (128x128 tile, BK=32, global_load_lds staging).
// Fragment maps (HW-verified): A[m=lane&15][k=quad*8+j],
// BT[n=lane&15][k=quad*8+j], C/D row=quad*4+reg, col=lane&15.
// ---------------------------------------------------------------------------
#define GEMM_PROLOG_128 \
    __shared__ __align__(16) short As[128][32]; \
    __shared__ __align__(16) short Bs[128][32]; \
    const int tid  = threadIdx.x; \
    const int wave = tid >> 6, lane = tid & 63; \
    const int quad = lane >> 4, l16 = lane & 15; \
    const int wr = (wave >> 1) * 64, wc = (wave & 1) * 64; \
    const int row0 = blockIdx.y * 128, col0 = blockIdx.x * 128; \
    const int srow = tid >> 2, scol = (tid & 3) * 8; \
    char* lAs0 = (char*)As + wave * 1024; \
    char* lAs1 = (char*)As + 4096 + wave * 1024; \
    char* lBs0 = (char*)Bs + wave * 1024; \
    char* lBs1 = (char*)Bs + 4096 + wave * 1024; \
    f32x4 acc[4][4]; \
    _Pragma("unroll") \
    for (int mt = 0; mt < 4; ++mt) \
        _Pragma("unroll") \
        for (int nt = 0; nt < 4; ++nt) \
            acc[mt][nt] = (f32x4){0.f, 0.f, 0.f, 0.f}; \
    for (int k0 = 0; k0 < K; k0 += 32) { \
        const short* ga = A  + (size_t)(row0 + srow) * K + k0 + scol; \
        const short* gb = BT + (size_t)(col0 + srow) * K + k0 + scol; \
        __syncthreads(); \
        gl2lds16(ga,                  lAs0); \
        gl2lds16(ga + (size_t)64 * K, lAs1); \
        gl2lds16(gb,                  lBs0); \
        gl2lds16(gb + (size_t)64 * K, lBs1); \
        __syncthreads(); \
        bf16x8 af[4], bfv[4]; \
        _Pragma("unroll") \
        for (int mt = 0; mt < 4; ++mt) \
            af[mt] = *(const bf16x8*)&As[wr + mt * 16 + l16][quad * 8]; \
        _Pragma("unroll") \
        for (int nt = 0; nt < 4; ++nt) \
            bfv[nt] = *(const bf16x8*)&Bs[wc + nt * 16 + l16][quad * 8]; \
        _Pragma("unroll") \
        for (int mt = 0; mt < 4; ++mt) \
            _Pragma("unroll") \
            for (int nt = 0; nt < 4; ++nt) \
                acc[mt][nt] = __builtin_amdgcn_mfma_f32_16x16x32_bf16( \
                    af[mt], bfv[nt], acc[mt][nt], 0, 0, 0); \
    }

template <typename OT>
__global__ __launch_bounds__(256)
void gemm_mfma(const short* __restrict__ A, const short* __restrict__ BT,
               OT* __restrict__ C, int M, int N, int K)
{
    GEMM_PROLOG_128
    #pragma unroll
    for (int mt = 0; mt < 4; ++mt)
        #pragma unroll
        for (int nt = 0; nt < 4; ++nt) {
            const int col = col0 + wc + nt * 16 + l16;
            #pragma unroll
            for (int r = 0; r < 4; ++r) {
                const int row = row0 + wr + mt * 16 + quad * 4 + r;
                stf(C + (size_t)row * N + col, acc[mt][nt][r]);
            }
        }
}

// ---------------------------------------------------------------------------
// gemm_qk: FUSED gemm_qrms (blocks 0..511) + gemm_k64 (blocks 512..639).
// Both read only xb; independent outputs (qn, kvb). k64 (latency-bound,
// 128 blocks) co-schedules with qrms (compute-bound) to fill CU bubbles.
// k64 path uses As[0..63][...] subset; block-uniform branch.
// ---------------------------------------------------------------------------
__global__ __launch_bounds__(256)
void gemm_qk(const short* __restrict__ xb, const short* __restrict__ wqT,
             const short* __restrict__ wkvT, bf16* __restrict__ qn,
             bf16* __restrict__ kvb, const float* __restrict__ qg)
{
    __shared__ __align__(16) short As[128][32];
    __shared__ __align__(16) short Bs[128][32];
    const int bid = blockIdx.x;
    const int tid  = threadIdx.x;
    const int wave = tid >> 6, lane = tid & 63;
    const int quad = lane >> 4, l16 = lane & 15;
    const int srow = tid >> 2, scol = (tid & 3) * 8;

    if (bid < 512) {                           // ===== qrms path =====
        const int K = DD;                      // 1024
        const int row0 = (bid >> 3) * 128, col0 = (bid & 7) * 128;
        const int wr = (wave >> 1) * 64, wc = (wave & 1) * 64;
        char* lAs0 = (char*)As + wave * 1024;
        char* lAs1 = (char*)As + 4096 + wave * 1024;
        char* lBs0 = (char*)Bs + wave * 1024;
        char* lBs1 = (char*)Bs + 4096 + wave * 1024;
        f32x4 acc[4][4];
        #pragma unroll
        for (int mt = 0; mt < 4; ++mt)
            #pragma unroll
            for (int nt = 0; nt < 4; ++nt)
                acc[mt][nt] = (f32x4){0.f, 0.f, 0.f, 0.f};
        for (int k0 = 0; k0 < K; k0 += 32) {
            const short* ga = xb  + (size_t)(row0 + srow) * K + k0 + scol;
            const short* gb = wqT + (size_t)(col0 + srow) * K + k0 + scol;
            __syncthreads();
            gl2lds16(ga,                  lAs0);
            gl2lds16(ga + (size_t)64 * K, lAs1);
            gl2lds16(gb,                  lBs0);
            gl2lds16(gb + (size_t)64 * K, lBs1);
            __syncthreads();
            bf16x8 af[4], bfv[4];
            #pragma unroll
            for (int mt = 0; mt < 4; ++mt)
                af[mt] = *(const bf16x8*)&As[wr + mt * 16 + l16][quad * 8];
            #pragma unroll
            for (int nt = 0; nt < 4; ++nt)
                bfv[nt] = *(const bf16x8*)&Bs[wc + nt * 16 + l16][quad * 8];
            #pragma unroll
            for (int mt = 0; mt < 4; ++mt)
                #pragma unroll
                for (int nt = 0; nt < 4; ++nt)
                    acc[mt][nt] = __builtin_amdgcn_mfma_f32_16x16x32_bf16(
                        af[mt], bfv[nt], acc[mt][nt], 0, 0, 0);
        }
        // fused Q-RMSNorm epilogue (qn pre-scaled by 0.125)
        const int h = (col0 + wc) >> 6;
        const float g0 = qg[l16], g1 = qg[16 + l16];
        #pragma unroll
        for (int mt = 0; mt < 4; ++mt) {
            float ss[4];
            #pragma unroll
            for (int r = 0; r < 4; ++r)
                ss[r] = acc[mt][0][r] * acc[mt][0][r] + acc[mt][1][r] * acc[mt][1][r]
                      + acc[mt][2][r] * acc[mt][2][r] + acc[mt][3][r] * acc[mt][3][r];
            #pragma unroll
            for (int off = 1; off < 16; off <<= 1)
                #pragma unroll
                for (int r = 0; r < 4; ++r) ss[r] += __shfl_xor(ss[r], off, 64);
            #pragma unroll
            for (int r = 0; r < 4; ++r) {
                const float inv = QSCALE_ / sqrtf(ss[r] * (1.0f / HD_) + EPS_);
                const int row = row0 + wr + mt * 16 + quad * 4 + r;
                const int b = row >> 11, t = row & 2047;
                bf16* op = qn + (((size_t)(b * HH + h)) * TT + t) * RP;
                op[l16]      = __float2bfloat16(g0 * acc[mt][0][r] * inv);
                op[16 + l16] = __float2bfloat16(g1 * acc[mt][1][r] * inv);
            }
        }
    } else {                                   // ===== k64 path =====
        const int K = DD, N = LAT_;            // 1024, 128
        const int row0 = (bid - 512) * 64, col0 = 0;
        const int wr = (wave >> 1) * 32, wc = (wave & 1) * 64;
        char* lAs  = (char*)As + wave * 1024;
        char* lBs0 = (char*)Bs + wave * 1024;
        char* lBs1 = (char*)Bs + 4096 + wave * 1024;
        f32x4 acc[2][4];
        #pragma unroll
        for (int mt = 0; mt < 2; ++mt)
            #pragma unroll
            for (int nt = 0; nt < 4; ++nt)
                acc[mt][nt] = (f32x4){0.f, 0.f, 0.f, 0.f};
        for (int k0 = 0; k0 < K; k0 += 32) {
            const short* ga = xb   + (size_t)(row0 + srow) * K + k0 + scol;
            const short* gb = wkvT + (size_t)(col0 + srow) * K + k0 + scol;
            __syncthreads();
            gl2lds16(ga,                  lAs);
            gl2lds16(gb,                  lBs0);
            gl2lds16(gb + (size_t)64 * K, lBs1);
            __syncthreads();
            bf16x8 af[2], bfv[4];
            #pragma unroll
            for (int mt = 0; mt < 2; ++mt)
                af[mt] = *(const bf16x8*)&As[wr + mt * 16 + l16][quad * 8];
            #pragma unroll
            for (int nt = 0; nt < 4; ++nt)
                bfv[nt] = *(const bf16x8*)&Bs[wc + nt * 16 + l16][quad * 8];
            #pragma unroll
            for (int mt = 0; mt < 2; ++mt)
                #pragma unroll
                for (int nt = 0; nt < 4; ++nt)
                    acc[mt][nt] = __builtin_amdgcn_mfma_f32_16x16x32_bf16(
                        af[mt], bfv[nt], acc[mt][nt], 0, 0, 0);
        }
        #pragma unroll
        for (int mt = 0; mt < 2; ++mt)
            #pragma unroll
            for (int nt = 0; nt < 4; ++nt) {
                const int col = col0 + wc + nt * 16 + l16;
                #pragma unroll
                for (int r = 0; r < 4; ++r) {
                    const int row = row0 + wr + mt * 16 + quad * 4 + r;
                    kvb[(size_t)row * N + col] = __float2bfloat16(acc[mt][nt][r]);
                }
            }
    }
}

// ---------------------------------------------------------------------------
// GEMM4 + fused K-RMSNorm / V-split epilogue. V path writes vT (bh,32,2048)
// DIRECTLY (transposed).
// ---------------------------------------------------------------------------
struct __attribute__((aligned(8))) bf4 { bf16 v[4]; };

__global__ __launch_bounds__(256)
void gemm_kv(const short* __restrict__ A, const short* __restrict__ BT,
             bf16* __restrict__ kn, bf16* __restrict__ vT,
             const float* __restrict__ kg, int M, int N, int K)
{
    GEMM_PROLOG_128
    const int colbase = col0 + wc;
    if (colbase < 512) {                        // K-RMS path
        const int h0 = colbase >> 5;            // groups h0, h0+1
        const float g0 = kg[l16], g1 = kg[16 + l16];
        #pragma unroll
        for (int mt = 0; mt < 4; ++mt) {
            float s0[4], s1[4];
            #pragma unroll
            for (int r = 0; r < 4; ++r) {
                s0[r] = acc[mt][0][r] * acc[mt][0][r] + acc[mt][1][r] * acc[mt][1][r];
                s1[r] = acc[mt][2][r] * acc[mt][2][r] + acc[mt][3][r] * acc[mt][3][r];
            }
            #pragma unroll
            for (int off = 1; off < 16; off <<= 1)
                #pragma unroll
                for (int r = 0; r < 4; ++r) {
                    s0[r] += __shfl_xor(s0[r], off, 64);
                    s1[r] += __shfl_xor(s1[r], off, 64);
                }
            #pragma unroll
            for (int r = 0; r < 4; ++r) {
                const float i0 = 1.0f / sqrtf(s0[r] * (1.0f / RP) + EPS_);
                const float i1 = 1.0f / sqrtf(s1[r] * (1.0f / RP) + EPS_);
                const int row = row0 + wr + mt * 16 + quad * 4 + r;
                const int b = row >> 11, t = row & 2047;
                bf16* op0 = kn + (((size_t)(b * HH + h0)) * TT + t) * RP;
                bf16* op1 = kn + (((size_t)(b * HH + h0 + 1)) * TT + t) * RP;
                op0[l16]      = __float2bfloat16(g0 * acc[mt][0][r] * i0);
                op0[16 + l16] = __float2bfloat16(g1 * acc[mt][1][r] * i0);
                op1[l16]      = __float2bfloat16(g0 * acc[mt][2][r] * i1);
                op1[16 + l16] = __float2bfloat16(g1 * acc[mt][3][r] * i1);
            }
        }
    } else {                                     // V path -> transposed vT
        const int h0 = (colbase - 512) >> 5;
        #pragma unroll
        for (int mt = 0; mt < 4; ++mt)
            #pragma unroll
            for (int nt = 0; nt < 4; ++nt) {
                const int h = h0 + (nt >> 1);
                const int c = (nt & 1) * 16 + l16;
                const int row = row0 + wr + mt * 16 + quad * 4;   // r=0 base
                const int b = row >> 11, t = row & 2047;
                bf4 pk;
                #pragma unroll
                for (int r = 0; r < 4; ++r)
                    pk.v[r] = __float2bfloat16(acc[mt][nt][r]);
                *(bf4*)(vT + (((size_t)(b * HH + h)) * RP + c) * TT + t) = pk;
            }
    }
}

// ---------------------------------------------------------------------------
// Flash MFMA attention (R15-verified): paired-tile single sweep, dbuf LDS
// staging w/ counted wait, XOR bank swizzle, fast __expf.
// ---------------------------------------------------------------------------
#define ATTN_TILE(QF, QB, LSUM, OA, OB)                                         \
    {                                                                           \
        f32x4 sc[4];                                                            \
        _Pragma("unroll")                                                       \
        for (int sub = 0; sub < 4; ++sub) {                                     \
            bf16x8 kf = *(const bf16x8*)&KsC[(sub * 16 + l16) * 32              \
                                             + ((quad ^ kslot) * 8)];           \
            sc[sub] = __builtin_amdgcn_mfma_f32_16x16x32_bf16(                  \
                kf, QF, (f32x4){0.f, 0.f, 0.f, 0.f}, 0, 0, 0);                  \
        }                                                                       \
        if (s0 + 63 > (QB)) {                                                   \
            const int qg_ = (QB) + l16;                                         \
            _Pragma("unroll")                                                   \
            for (int sub = 0; sub < 4; ++sub)                                   \
                _Pragma("unroll")                                               \
                for (int r = 0; r < 4; ++r)                                     \
                    if (s0 + sub * 16 + quad * 4 + r > qg_) sc[sub][r] = -1e30f;\
        }                                                                       \
        _Pragma("unroll")                                                       \
        for (int sub = 0; sub < 4; ++sub) {                                     \
            const float p0 = __expf(sc[sub][0]);                                \
            const float p1 = __expf(sc[sub][1]);                                \
            const float p2 = __expf(sc[sub][2]);                                \
            const float p3 = __expf(sc[sub][3]);                                \
            bf4 pk;                                                             \
            pk.v[0] = __float2bfloat16(p0);                                     \
            pk.v[1] = __float2bfloat16(p1);                                     \
            pk.v[2] = __float2bfloat16(p2);                                     \
            pk.v[3] = __float2bfloat16(p3);                                     \
            *(bf4*)&P_lds[w8][l16][sub * 16 + quad * 4] = pk;                   \
            LSUM += (p0 + p1) + (p2 + p3);                                      \
        }                                                                       \
        _Pragma("unroll")                                                       \
        for (int ks = 0; ks < 2; ++ks) {                                        \
            bf16x8 pf  = *(const bf16x8*)&P_lds[w8][l16][ks * 32 + quad * 8];   \
            bf16x8 vf0 = *(const bf16x8*)&VsC[l16 * 64                          \
                            + (((ks * 4 + quad) ^ vswz) * 8)];                  \
            bf16x8 vf1 = *(const bf16x8*)&VsC[(16 + l16) * 64                   \
                            + (((ks * 4 + quad) ^ vswz) * 8)];                  \
            OA = __builtin_amdgcn_mfma_f32_16x16x32_bf16(pf, vf0, OA, 0, 0, 0); \
            OB = __builtin_amdgcn_mfma_f32_16x16x32_bf16(pf, vf1, OB, 0, 0, 0); \
        }                                                                       \
    }

#define ATTN_EPI(QB, LSUM, OA, OB)                                              \
    {                                                                           \
        float ls_ = (LSUM);                                                     \
        ls_ += __shfl_xor(ls_, 16, 64);                                         \
        ls_ += __shfl_xor(ls_, 32, 64);                                         \
        _Pragma("unroll")                                                       \
        for (int r = 0; r < 4; ++r) {                                           \
            const float lr  = __shfl(ls_, quad * 20 + r, 64);                   \
            const float inv = 1.0f / lr;                                        \
            const int t = (QB) + quad * 4 + r;                                  \
            bf16* op = att + ((size_t)(b * TT + t)) * 512 + h * 32;             \
            op[l16]      = __float2bfloat16((OA)[r] * inv);                     \
            op[16 + l16] = __float2bfloat16((OB)[r] * inv);                     \
        }                                                                       \
    }

__global__ __launch_bounds__(512, 4)
void attn_mfma(const bf16* __restrict__ qn, const bf16* __restrict__ kn,
               const bf16* __restrict__ vT, bf16* __restrict__ att)
{
    __shared__ __align__(16) short KsF[2][64 * 32];   // 8 KB, swizzled slots
    __shared__ __align__(16) short VsF[2][32 * 64];   // 8 KB, swizzled slots
    __shared__ __align__(16) bf16 P_lds[8][16][72];   // 18 KB
    const int tid  = threadIdx.x;
    const int w8   = tid >> 6, lane = tid & 63;
    const int quad = lane >> 4, l16 = lane & 15;
    // XCD-aware bijective remap: f -> (bx 0..7, bh 0..63), bh%8 == xcd
    const int f  = (int)(blockIdx.y * 8 + blockIdx.x);     // 0..511
    const int xr = f & 7, j = f >> 3;                       // j: 0..63
    const int bx = j & 7;
    const int bh = xr + 8 * (j >> 3);
    const int b = bh >> 4, h = bh & 15;

    const bf16* knb = kn + (size_t)bh * TT * RP;
    const bf16* vtb = vT + (size_t)bh * RP * TT;

    // staging map (LDS dest linear within buffer; source pre-swizzled)
    const bool isK = (w8 < 4);
    const int  cK = tid;
    const int  cV = tid - 256;
    const bf16* sBase = isK
        ? knb + (size_t)(cK >> 2) * RP + ((cK & 3) ^ ((cK >> 3) & 3)) * 8
        : vtb + (size_t)(cV >> 3) * TT + ((cV & 7) ^ ((cV >> 3) & 7)) * 8;
    const long long sStep = (long long)(isK ? RP : 1) * 64;  // per 64-row step
    const int ldsOff = isK ? w8 * 1024 : (w8 - 4) * 1024;

    // swizzled read offsets (in shorts)
    const int kslot = ((l16 >> 1) & 3);     // K frag: (quad^kslot)*8
    const int vswz  = (l16 & 7);            // V frag: ((ks*4+quad)^vswz)*8

    // paired tiles: A = bx (short), B = 15-bx (long); NTA < NTB always
    const int NTA = 2 * bx + 2, NTB = 32 - 2 * bx;
    const int qbaseA = bx * 128 + w8 * 16;
    const int qbaseB = (15 - bx) * 128 + w8 * 16;

    bf16x8 qfA = *(const bf16x8*)(qn + ((size_t)bh * TT + qbaseA + l16) * RP + quad * 8);
    bf16x8 qfB = *(const bf16x8*)(qn + ((size_t)bh * TT + qbaseB + l16) * RP + quad * 8);

    float lsumA = 0.f, lsumB = 0.f;
    f32x4 oA0 = (f32x4){0.f, 0.f, 0.f, 0.f};
    f32x4 oA1 = (f32x4){0.f, 0.f, 0.f, 0.f};
    f32x4 oB0 = (f32x4){0.f, 0.f, 0.f, 0.f};
    f32x4 oB1 = (f32x4){0.f, 0.f, 0.f, 0.f};

    // prologue: stage step 0 into buffer 0
    gl2lds16(sBase, (isK ? (char*)KsF[0] : (char*)VsF[0]) + ldsOff);
    int cur = 0;

    for (int st = 0; st < NTB; ++st) {
        asm volatile("s_waitcnt vmcnt(0)\n\ts_barrier" ::: "memory");

        const int nxt = cur ^ 1;
        gl2lds16(sBase + (long long)(st + 1) * sStep,
                 (isK ? (char*)KsF[nxt] : (char*)VsF[nxt]) + ldsOff);

        const int s0 = st * 64;
        const short* KsC = KsF[cur];
        const short* VsC = VsF[cur];

        ATTN_TILE(qfB, qbaseB, lsumB, oB0, oB1)
        if (st < NTA) {                        // block-uniform branch
            ATTN_TILE(qfA, qbaseA, lsumA, oA0, oA1)
        }
        cur = nxt;
    }

    ATTN_EPI(qbaseA, lsumA, oA0, oA1)
    ATTN_EPI(qbaseB, lsumB, oB0, oB1)
}

// ---------------------------------------------------------------------------
// Workspace (BYTE offsets from base = d_ws + 64):
//   xb    bf16 [0, 16777216)            (dead after gemm_qk)
//   wqT   bf16 [16777216, 18874368)     (dead after gemm_qk)
//   wkvT  bf16 [18874368, 19136512)     (dead after gemm_qk)
//   kvb   bf16 [19136512, 21233664)     (dead after gemm_kv)
//   att_b bf16 [0, 8388608)             (alias over dead xb lower half)
//   vTb   bf16 [8388608, 16777216)      (alias over dead xb upper half;
//                                        written directly by gemm_kv)
//   qn    bf16 [35913728, 44302336)
//   kn    bf16 [44302336, 52690944)     (attn tail prefetch -> old vb region,
//                                        harmless: mapped workspace)
//   wkwvT bf16 [61079552, 61341696)
//   woT   bf16 [61341696, 62390272)
// ---------------------------------------------------------------------------
extern "C" void kernel_launch(void* const* d_in, const int* in_sizes, int n_in,
                              void* d_out, int out_size, void* d_ws, size_t ws_size,
                              hipStream_t stream)
{
    float* out = (float*)d_out;
    const long long NOUT = (long long)BB * TT * DD;
    const int outgrid = (int)((NOUT + 255) / 256);

    static const long long expect[8] =
        {8388608, 1048576, 131072, 65536, 65536, 1048576, 64, 32};
    if (n_in != 8) {
        sentinel_kernel<<<outgrid, 256, 0, stream>>>(out, 20000.0f + 100.0f * n_in, NOUT);
        return;
    }
    for (int i = 0; i < 8; ++i) {
        if ((long long)in_sizes[i] != expect[i]) {
            sentinel_kernel<<<outgrid, 256, 0, stream>>>(out, 10000.0f + 1000.0f * i, NOUT);
            return;
        }
    }
    if (ws_size < 62914624ULL) {
        sentinel_kernel<<<outgrid, 256, 0, stream>>>(
            out, 30000.0f + (float)(ws_size >> 20), NOUT);
        return;
    }
    if (out_size != 8388608) {
        sentinel_kernel<<<outgrid, 256, 0, stream>>>(
            out, 512.0f * (1.0f + (float)(out_size >> 20)), NOUT);
        return;
    }

    const float* x   = (const float*)d_in[0];
    const float* Wq  = (const float*)d_in[1];
    const float* Wkv = (const float*)d_in[2];
    const float* Wk  = (const float*)d_in[3];
    const float* Wv  = (const float*)d_in[4];
    const float* Wo  = (const float*)d_in[5];
    const float* qg  = (const float*)d_in[6];
    const float* kg  = (const float*)d_in[7];

    char* base = (char*)d_ws + 64;
    bf16*  xb    = (bf16*)(base + 0);
    bf16*  wqT   = (bf16*)(base + 16777216);
    bf16*  wkvT  = (bf16*)(base + 18874368);
    bf16*  kvb   = (bf16*)(base + 19136512);
    bf16*  att_b = (bf16*)(base + 0);
    bf16*  vTb   = (bf16*)(base + 8388608);
    bf16*  qn    = (bf16*)(base + 35913728);
    bf16*  kn    = (bf16*)(base + 44302336);
    bf16*  wkwvT = (bf16*)(base + 61079552);
    bf16*  woT   = (bf16*)(base + 61341696);

    const int BT = BB * TT;                    // 8192

    // 1. ALL converts in one dispatch
    conv_all<<<9120, 256, 0, stream>>>(x, xb, Wq, wqT, Wkv, wkvT,
                                       Wk, Wv, wkwvT, Wo, woT);
    // 2. FUSED qrms-GEMM (512 blocks) + kv-compression GEMM (128 blocks)
    gemm_qk<<<640, 256, 0, stream>>>(
        (const short*)xb, (const short*)wqT, (const short*)wkvT, qn, kvb, qg);
    // 3. kn / vT = fused(kvb @ [Wk|Wv]) (K-RMS + transposed V write)
    gemm_kv<<<dim3(8, 64), 256, 0, stream>>>(
        (const short*)kvb, (const short*)wkwvT, kn, vTb, kg, BT, 2 * 512, LAT_);
    // 4. flash MFMA attention (paired-tile sweep, dbuf staging, __expf)
    attn_mfma<<<dim3(8, 64), 512, 0, stream>>>(qn, kn, vTb, att_b);
    // 5. out = att_b @ Wo_remap (MFMA), 8192x1024, K=512
    gemm_mfma<float><<<dim3(8, 64), 256, 0, stream>>>(
        (const short*)att_b, (const short*)woT, out, BT, DD, 512);
}

// Round 17
// 196.083 us; speedup vs baseline: 1.2160x; 1.0363x over previous
//
#include <hip/hip_runtime.h>
#include <hip/hip_bf16.h>
#include <math.h>

using bf16 = __hip_bfloat16;
typedef __attribute__((ext_vector_type(8))) short bf16x8;
typedef __attribute__((ext_vector_type(4))) float f32x4;

#define BB   4
#define TT   2048
#define DD   1024
#define HH   16
#define HD_  64
#define LAT_ 128
#define RP   32
#define EPS_ 1e-6f
#define QSCALE_ 0.125f

static __device__ __forceinline__ void stf(float* p, float v) { *p = v; }
static __device__ __forceinline__ void stf(bf16* p, float v) { *p = __float2bfloat16(v); }

// global -> LDS 16B DMA (wave-uniform LDS base + lane*16)
static __device__ __forceinline__ void gl2lds16(const void* g, void* l)
{
    __builtin_amdgcn_global_load_lds(
        (const __attribute__((address_space(1))) void*)g,
        (__attribute__((address_space(3))) void*)l, 16, 0, 0);
}

__global__ __launch_bounds__(256)
void sentinel_kernel(float* __restrict__ out, float val, long long n)
{
    long long i = (long long)blockIdx.x * 256 + threadIdx.x;
    if (i < n) out[i] = val;
}

// ---------------------------------------------------------------------------
// conv_all: ALL input conversions in ONE dispatch (flat-id partition).
// ---------------------------------------------------------------------------
__global__ __launch_bounds__(256)
void conv_all(const float* __restrict__ x,  bf16* __restrict__ xb,
              const float* __restrict__ Wq, bf16* __restrict__ wqT,
              const float* __restrict__ Wkv, bf16* __restrict__ wkvT,
              const float* __restrict__ Wk, const float* __restrict__ Wv,
              bf16* __restrict__ wkwvT,
              const float* __restrict__ Wo, bf16* __restrict__ woT)
{
    __shared__ __align__(16) bf16 t[64][72];
    const int bid = blockIdx.x;
    const int tid = threadIdx.x;

    if (bid < 8192) {                          // ---- conv_x ----
        const long long i = (long long)bid * 256 + tid;   // x4 elems
        float4 v = *(const float4*)(x + i * 4);
        union { bf16 h[4]; uint2 u; } o;
        o.h[0] = __float2bfloat16(v.x);
        o.h[1] = __float2bfloat16(v.y);
        o.h[2] = __float2bfloat16(v.z);
        o.h[3] = __float2bfloat16(v.w);
        *(uint2*)(xb + i * 4) = o.u;
        return;
    }
    if (bid < 8480) {                          // ---- transpose-convert ----
        const float* W; bf16* WT; int K, N, bx, by;
        if (bid < 8448) { W = Wq;  WT = wqT;  K = 1024; N = 1024;
                          bx = (bid - 8192) & 15; by = (bid - 8192) >> 4; }
        else            { W = Wkv; WT = wkvT; K = 1024; N = 128;
                          bx = (bid - 8448) & 1;  by = (bid - 8448) >> 1; }
        const int k0 = by * 64, n0 = bx * 64;
        const int r = tid >> 2, c0 = (tid & 3) * 16;
        const float* src = W + (size_t)(k0 + r) * N + n0 + c0;
        #pragma unroll
        for (int j = 0; j < 16; j += 4) {
            float4 v = *(const float4*)(src + j);
            t[c0 + j + 0][r] = __float2bfloat16(v.x);
            t[c0 + j + 1][r] = __float2bfloat16(v.y);
            t[c0 + j + 2][r] = __float2bfloat16(v.z);
            t[c0 + j + 3][r] = __float2bfloat16(v.w);
        }
        __syncthreads();
        const int rr = tid >> 2, cc = (tid & 3) * 16;
        bf16* dst = WT + (size_t)(n0 + rr) * K + k0 + cc;
        *(bf16x8*)dst       = *(const bf16x8*)&t[rr][cc];
        *(bf16x8*)(dst + 8) = *(const bf16x8*)&t[rr][cc + 8];
        return;
    }
    if (bid < 8992) {                          // ---- [Wk|Wv] -> wkwvT ----
        int idx = (bid - 8480) * 256 + tid;    // 128*1024
        int k = idx >> 10, n = idx & 1023;
        float v = (n < 512) ? Wk[k * 512 + n] : Wv[k * 512 + (n - 512)];
        wkwvT[(size_t)n * 128 + k] = __float2bfloat16(v);
        return;
    }
    {                                          // ---- Wo -> woT (remap) ----
        const int id = bid - 8992;             // grid (16 n-tiles, 8 mm-tiles)
        const int bx = id & 15, by = id >> 4;
        const int mm0 = by * 64, n0 = bx * 64;
        const int r = tid >> 2, c0 = (tid & 3) * 16;
        const int mm = mm0 + r;
        const int row = ((mm >> 5) << 6) | (mm & 31);
        const float* src = Wo + (size_t)row * 1024 + n0 + c0;
        #pragma unroll
        for (int j = 0; j < 16; j += 4) {
            float4 v = *(const float4*)(src + j);
            t[c0 + j + 0][r] = __float2bfloat16(v.x);
            t[c0 + j + 1][r] = __float2bfloat16(v.y);
            t[c0 + j + 2][r] = __float2bfloat16(v.z);
            t[c0 + j + 3][r] = __float2bfloat16(v.w);
        }
        __syncthreads();
        const int rr = tid >> 2, cc = (tid & 3) * 16;
        bf16* dst = woT + (size_t)(n0 + rr) * 512 + mm0 + cc;
        *(bf16x8*)dst       = *(const bf16x8*)&t[rr][cc];
        *(bf16x8*)(dst + 8) = *(const bf16x8*)&t[rr][cc + 8];
    }
}

// ---------------------------------------------------------------------------
// MFMA GEMM prolog (128x128 tile, BK=32, global_load_lds staging) with
// XCD-AWARE block remap: for grids of exactly (8 cols, 64 rows), flat id
// f = by*8+bx is remapped so all 8 col-blocks of one row share f%8 (=XCD
// under round-robin) -> A-slab fetched once per XCD instead of 8x.
// Bijection: x=f&7, g=f>>3; row=((g>>3)<<3)|x, col=g&7.
// Fragment maps (HW-verified): A[m=lane&15][k=quad*8+j],
// BT[n=lane&15][k=quad*8+j], C/D row=quad*4+reg, col=lane&15.
// ---------------------------------------------------------------------------
#define GEMM_PROLOG_128 \
    __shared__ __align__(16) short As[128][32]; \
    __shared__ __align__(16) short Bs[128][32]; \
    const int tid  = threadIdx.x; \
    const int wave = tid >> 6, lane = tid & 63; \
    const int quad = lane >> 4, l16 = lane & 15; \
    const int wr = (wave >> 1) * 64, wc = (wave & 1) * 64; \
    const int f_  = (int)(blockIdx.y * 8 + blockIdx.x); \
    const int x_  = f_ & 7, g_ = f_ >> 3; \
    const int row0 = ((((g_ >> 3) << 3) | x_)) * 128; \
    const int col0 = (g_ & 7) * 128; \
    const int srow = tid >> 2, scol = (tid & 3) * 8; \
    char* lAs0 = (char*)As + wave * 1024; \
    char* lAs1 = (char*)As + 4096 + wave * 1024; \
    char* lBs0 = (char*)Bs + wave * 1024; \
    char* lBs1 = (char*)Bs + 4096 + wave * 1024; \
    f32x4 acc[4][4]; \
    _Pragma("unroll") \
    for (int mt = 0; mt < 4; ++mt) \
        _Pragma("unroll") \
        for (int nt = 0; nt < 4; ++nt) \
            acc[mt][nt] = (f32x4){0.f, 0.f, 0.f, 0.f}; \
    for (int k0 = 0; k0 < K; k0 += 32) { \
        const short* ga = A  + (size_t)(row0 + srow) * K + k0 + scol; \
        const short* gb = BT + (size_t)(col0 + srow) * K + k0 + scol; \
        __syncthreads(); \
        gl2lds16(ga,                  lAs0); \
        gl2lds16(ga + (size_t)64 * K, lAs1); \
        gl2lds16(gb,                  lBs0); \
        gl2lds16(gb + (size_t)64 * K, lBs1); \
        __syncthreads(); \
        bf16x8 af[4], bfv[4]; \
        _Pragma("unroll") \
        for (int mt = 0; mt < 4; ++mt) \
            af[mt] = *(const bf16x8*)&As[wr + mt * 16 + l16][quad * 8]; \
        _Pragma("unroll") \
        for (int nt = 0; nt < 4; ++nt) \
            bfv[nt] = *(const bf16x8*)&Bs[wc + nt * 16 + l16][quad * 8]; \
        _Pragma("unroll") \
        for (int mt = 0; mt < 4; ++mt) \
            _Pragma("unroll") \
            for (int nt = 0; nt < 4; ++nt) \
                acc[mt][nt] = __builtin_amdgcn_mfma_f32_16x16x32_bf16( \
                    af[mt], bfv[nt], acc[mt][nt], 0, 0, 0); \
    }

template <typename OT>
__global__ __launch_bounds__(256)
void gemm_mfma(const short* __restrict__ A, const short* __restrict__ BT,
               OT* __restrict__ C, int M, int N, int K)
{
    GEMM_PROLOG_128
    #pragma unroll
    for (int mt = 0; mt < 4; ++mt)
        #pragma unroll
        for (int nt = 0; nt < 4; ++nt) {
            const int col = col0 + wc + nt * 16 + l16;
            #pragma unroll
            for (int r = 0; r < 4; ++r) {
                const int row = row0 + wr + mt * 16 + quad * 4 + r;
                stf(C + (size_t)row * N + col, acc[mt][nt][r]);
            }
        }
}

// ---------------------------------------------------------------------------
// gemm_qk: FUSED gemm_qrms (blocks 0..511, XCD-remapped) + gemm_k64
// (blocks 512..639). Both read only xb; independent outputs (qn, kvb).
// ---------------------------------------------------------------------------
__global__ __launch_bounds__(256)
void gemm_qk(const short* __restrict__ xb, const short* __restrict__ wqT,
             const short* __restrict__ wkvT, bf16* __restrict__ qn,
             bf16* __restrict__ kvb, const float* __restrict__ qg)
{
    __shared__ __align__(16) short As[128][32];
    __shared__ __align__(16) short Bs[128][32];
    const int bid = blockIdx.x;
    const int tid  = threadIdx.x;
    const int wave = tid >> 6, lane = tid & 63;
    const int quad = lane >> 4, l16 = lane & 15;
    const int srow = tid >> 2, scol = (tid & 3) * 8;

    if (bid < 512) {                           // ===== qrms path =====
        const int K = DD;                      // 1024
        // XCD-aware remap: all 8 col-blocks of a row share bid%8 (=XCD)
        const int x_ = bid & 7, g_ = bid >> 3;
        const int row0 = ((((g_ >> 3) << 3) | x_)) * 128;
        const int col0 = (g_ & 7) * 128;
        const int wr = (wave >> 1) * 64, wc = (wave & 1) * 64;
        char* lAs0 = (char*)As + wave * 1024;
        char* lAs1 = (char*)As + 4096 + wave * 1024;
        char* lBs0 = (char*)Bs + wave * 1024;
        char* lBs1 = (char*)Bs + 4096 + wave * 1024;
        f32x4 acc[4][4];
        #pragma unroll
        for (int mt = 0; mt < 4; ++mt)
            #pragma unroll
            for (int nt = 0; nt < 4; ++nt)
                acc[mt][nt] = (f32x4){0.f, 0.f, 0.f, 0.f};
        for (int k0 = 0; k0 < K; k0 += 32) {
            const short* ga = xb  + (size_t)(row0 + srow) * K + k0 + scol;
            const short* gb = wqT + (size_t)(col0 + srow) * K + k0 + scol;
            __syncthreads();
            gl2lds16(ga,                  lAs0);
            gl2lds16(ga + (size_t)64 * K, lAs1);
            gl2lds16(gb,                  lBs0);
            gl2lds16(gb + (size_t)64 * K, lBs1);
            __syncthreads();
            bf16x8 af[4], bfv[4];
            #pragma unroll
            for (int mt = 0; mt < 4; ++mt)
                af[mt] = *(const bf16x8*)&As[wr + mt * 16 + l16][quad * 8];
            #pragma unroll
            for (int nt = 0; nt < 4; ++nt)
                bfv[nt] = *(const bf16x8*)&Bs[wc + nt * 16 + l16][quad * 8];
            #pragma unroll
            for (int mt = 0; mt < 4; ++mt)
                #pragma unroll
                for (int nt = 0; nt < 4; ++nt)
                    acc[mt][nt] = __builtin_amdgcn_mfma_f32_16x16x32_bf16(
                        af[mt], bfv[nt], acc[mt][nt], 0, 0, 0);
        }
        // fused Q-RMSNorm epilogue (qn pre-scaled by 0.125)
        const int h = (col0 + wc) >> 6;
        const float g0 = qg[l16], g1 = qg[16 + l16];
        #pragma unroll
        for (int mt = 0; mt < 4; ++mt) {
            float ss[4];
            #pragma unroll
            for (int r = 0; r < 4; ++r)
                ss[r] = acc[mt][0][r] * acc[mt][0][r] + acc[mt][1][r] * acc[mt][1][r]
                      + acc[mt][2][r] * acc[mt][2][r] + acc[mt][3][r] * acc[mt][3][r];
            #pragma unroll
            for (int off = 1; off < 16; off <<= 1)
                #pragma unroll
                for (int r = 0; r < 4; ++r) ss[r] += __shfl_xor(ss[r], off, 64);
            #pragma unroll
            for (int r = 0; r < 4; ++r) {
                const float inv = QSCALE_ / sqrtf(ss[r] * (1.0f / HD_) + EPS_);
                const int row = row0 + wr + mt * 16 + quad * 4 + r;
                const int b = row >> 11, t = row & 2047;
                bf16* op = qn + (((size_t)(b * HH + h)) * TT + t) * RP;
                op[l16]      = __float2bfloat16(g0 * acc[mt][0][r] * inv);
                op[16 + l16] = __float2bfloat16(g1 * acc[mt][1][r] * inv);
            }
        }
    } else {                                   // ===== k64 path =====
        const int K = DD, N = LAT_;            // 1024, 128
        const int row0 = (bid - 512) * 64, col0 = 0;
        const int wr = (wave >> 1) * 32, wc = (wave & 1) * 64;
        char* lAs  = (char*)As + wave * 1024;
        char* lBs0 = (char*)Bs + wave * 1024;
        char* lBs1 = (char*)Bs + 4096 + wave * 1024;
        f32x4 acc[2][4];
        #pragma unroll
        for (int mt = 0; mt < 2; ++mt)
            #pragma unroll
            for (int nt = 0; nt < 4; ++nt)
                acc[mt][nt] = (f32x4){0.f, 0.f, 0.f, 0.f};
        for (int k0 = 0; k0 < K; k0 += 32) {
            const short* ga = xb   + (size_t)(row0 + srow) * K + k0 + scol;
            const short* gb = wkvT + (size_t)(col0 + srow) * K + k0 + scol;
            __syncthreads();
            gl2lds16(ga,                  lAs);
            gl2lds16(gb,                  lBs0);
            gl2lds16(gb + (size_t)64 * K, lBs1);
            __syncthreads();
            bf16x8 af[2], bfv[4];
            #pragma unroll
            for (int mt = 0; mt < 2; ++mt)
                af[mt] = *(const bf16x8*)&As[wr + mt * 16 + l16][quad * 8];
            #pragma unroll
            for (int nt = 0; nt < 4; ++nt)
                bfv[nt] = *(const bf16x8*)&Bs[wc + nt * 16 + l16][quad * 8];
            #pragma unroll
            for (int mt = 0; mt < 2; ++mt)
                #pragma unroll
                for (int nt = 0; nt < 4; ++nt)
                    acc[mt][nt] = __builtin_amdgcn_mfma_f32_16x16x32_bf16(
                        af[mt], bfv[nt], acc[mt][nt], 0, 0, 0);
        }
        #pragma unroll
        for (int mt = 0; mt < 2; ++mt)
            #pragma unroll
            for (int nt = 0; nt < 4; ++nt) {
                const int col = col0 + wc + nt * 16 + l16;
                #pragma unroll
                for (int r = 0; r < 4; ++r) {
                    const int row = row0 + wr + mt * 16 + quad * 4 + r;
                    kvb[(size_t)row * N + col] = __float2bfloat16(acc[mt][nt][r]);
                }
            }
    }
}

// ---------------------------------------------------------------------------
// GEMM4 + fused K-RMSNorm / V-split epilogue (XCD-remapped via prolog).
// V path writes vT (bh,32,2048) DIRECTLY (transposed).
// ---------------------------------------------------------------------------
struct __attribute__((aligned(8))) bf4 { bf16 v[4]; };

__global__ __launch_bounds__(256)
void gemm_kv(const short* __restrict__ A, const short* __restrict__ BT,
             bf16* __restrict__ kn, bf16* __restrict__ vT,
             const float* __restrict__ kg, int M, int N, int K)
{
    GEMM_PROLOG_128
    const int colbase = col0 + wc;
    if (colbase < 512) {                        // K-RMS path
        const int h0 = colbase >> 5;            // groups h0, h0+1
        const float g0 = kg[l16], g1 = kg[16 + l16];
        #pragma unroll
        for (int mt = 0; mt < 4; ++mt) {
            float s0[4], s1[4];
            #pragma unroll
            for (int r = 0; r < 4; ++r) {
                s0[r] = acc[mt][0][r] * acc[mt][0][r] + acc[mt][1][r] * acc[mt][1][r];
                s1[r] = acc[mt][2][r] * acc[mt][2][r] + acc[mt][3][r] * acc[mt][3][r];
            }
            #pragma unroll
            for (int off = 1; off < 16; off <<= 1)
                #pragma unroll
                for (int r = 0; r < 4; ++r) {
                    s0[r] += __shfl_xor(s0[r], off, 64);
                    s1[r] += __shfl_xor(s1[r], off, 64);
                }
            #pragma unroll
            for (int r = 0; r < 4; ++r) {
                const float i0 = 1.0f / sqrtf(s0[r] * (1.0f / RP) + EPS_);
                const float i1 = 1.0f / sqrtf(s1[r] * (1.0f / RP) + EPS_);
                const int row = row0 + wr + mt * 16 + quad * 4 + r;
                const int b = row >> 11, t = row & 2047;
                bf16* op0 = kn + (((size_t)(b * HH + h0)) * TT + t) * RP;
                bf16* op1 = kn + (((size_t)(b * HH + h0 + 1)) * TT + t) * RP;
                op0[l16]      = __float2bfloat16(g0 * acc[mt][0][r] * i0);
                op0[16 + l16] = __float2bfloat16(g1 * acc[mt][1][r] * i0);
                op1[l16]      = __float2bfloat16(g0 * acc[mt][2][r] * i1);
                op1[16 + l16] = __float2bfloat16(g1 * acc[mt][3][r] * i1);
            }
        }
    } else {                                     // V path -> transposed vT
        const int h0 = (colbase - 512) >> 5;
        #pragma unroll
        for (int mt = 0; mt < 4; ++mt)
            #pragma unroll
            for (int nt = 0; nt < 4; ++nt) {
                const int h = h0 + (nt >> 1);
                const int c = (nt & 1) * 16 + l16;
                const int row = row0 + wr + mt * 16 + quad * 4;   // r=0 base
                const int b = row >> 11, t = row & 2047;
                bf4 pk;
                #pragma unroll
                for (int r = 0; r < 4; ++r)
                    pk.v[r] = __float2bfloat16(acc[mt][nt][r]);
                *(bf4*)(vT + (((size_t)(b * HH + h)) * RP + c) * TT + t) = pk;
            }
    }
}

// ---------------------------------------------------------------------------
// Flash MFMA attention (R15-verified): paired-tile single sweep, dbuf LDS
// staging w/ counted wait, XOR bank swizzle, fast __expf.
// ---------------------------------------------------------------------------
#define ATTN_TILE(QF, QB, LSUM, OA, OB)                                         \
    {                                                                           \
        f32x4 sc[4];                                                            \
        _Pragma("unroll")                                                       \
        for (int sub = 0; sub < 4; ++sub) {                                     \
            bf16x8 kf = *(const bf16x8*)&KsC[(sub * 16 + l16) * 32              \
                                             + ((quad ^ kslot) * 8)];           \
            sc[sub] = __builtin_amdgcn_mfma_f32_16x16x32_bf16(                  \
                kf, QF, (f32x4){0.f, 0.f, 0.f, 0.f}, 0, 0, 0);                  \
        }                                                                       \
        if (s0 + 63 > (QB)) {                                                   \
            const int qg_ = (QB) + l16;                                         \
            _Pragma("unroll")                                                   \
            for (int sub = 0; sub < 4; ++sub)                                   \
                _Pragma("unroll")                                               \
                for (int r = 0; r < 4; ++r)                                     \
                    if (s0 + sub * 16 + quad * 4 + r > qg_) sc[sub][r] = -1e30f;\
        }                                                                       \
        _Pragma("unroll")                                                       \
        for (int sub = 0; sub < 4; ++sub) {                                     \
            const float p0 = __expf(sc[sub][0]);                                \
            const float p1 = __expf(sc[sub][1]);                                \
            const float p2 = __expf(sc[sub][2]);                                \
            const float p3 = __expf(sc[sub][3]);                                \
            bf4 pk;                                                             \
            pk.v[0] = __float2bfloat16(p0);                                     \
            pk.v[1] = __float2bfloat16(p1);                                     \
            pk.v[2] = __float2bfloat16(p2);                                     \
            pk.v[3] = __float2bfloat16(p3);                                     \
            *(bf4*)&P_lds[w8][l16][sub * 16 + quad * 4] = pk;                   \
            LSUM += (p0 + p1) + (p2 + p3);                                      \
        }                                                                       \
        _Pragma("unroll")                                                       \
        for (int ks = 0; ks < 2; ++ks) {                                        \
            bf16x8 pf  = *(const bf16x8*)&P_lds[w8][l16][ks * 32 + quad * 8];   \
            bf16x8 vf0 = *(const bf16x8*)&VsC[l16 * 64                          \
                            + (((ks * 4 + quad) ^ vswz) * 8)];                  \
            bf16x8 vf1 = *(const bf16x8*)&VsC[(16 + l16) * 64                   \
                            + (((ks * 4 + quad) ^ vswz) * 8)];                  \
            OA = __builtin_amdgcn_mfma_f32_16x16x32_bf16(pf, vf0, OA, 0, 0, 0); \
            OB = __builtin_amdgcn_mfma_f32_16x16x32_bf16(pf, vf1, OB, 0, 0, 0); \
        }                                                                       \
    }

#define ATTN_EPI(QB, LSUM, OA, OB)                                              \
    {                                                                           \
        float ls_ = (LSUM);                                                     \
        ls_ += __shfl_xor(ls_, 16, 64);                                         \
        ls_ += __shfl_xor(ls_, 32, 64);                                         \
        _Pragma("unroll")                                                       \
        for (int r = 0; r < 4; ++r) {                                           \
            const float lr  = __shfl(ls_, quad * 20 + r, 64);                   \
            const float inv = 1.0f / lr;                                        \
            const int t = (QB) + quad * 4 + r;                                  \
            bf16* op = att + ((size_t)(b * TT + t)) * 512 + h * 32;             \
            op[l16]      = __float2bfloat16((OA)[r] * inv);                     \
            op[16 + l16] = __float2bfloat16((OB)[r] * inv);                     \
        }                                                                       \
    }

__global__ __launch_bounds__(512, 4)
void attn_mfma(const bf16* __restrict__ qn, const bf16* __restrict__ kn,
               const bf16* __restrict__ vT, bf16* __restrict__ att)
{
    __shared__ __align__(16) short KsF[2][64 * 32];   // 8 KB, swizzled slots
    __shared__ __align__(16) short VsF[2][32 * 64];   // 8 KB, swizzled slots
    __shared__ __align__(16) bf16 P_lds[8][16][72];   // 18 KB
    const int tid  = threadIdx.x;
    const int w8   = tid >> 6, lane = tid & 63;
    const int quad = lane >> 4, l16 = lane & 15;
    // XCD-aware bijective remap: f -> (bx 0..7, bh 0..63), bh%8 == xcd
    const int f  = (int)(blockIdx.y * 8 + blockIdx.x);     // 0..511
    const int xr = f & 7, j = f >> 3;                       // j: 0..63
    const int bx = j & 7;
    const int bh = xr + 8 * (j >> 3);
    const int b = bh >> 4, h = bh & 15;

    const bf16* knb = kn + (size_t)bh * TT * RP;
    const bf16* vtb = vT + (size_t)bh * RP * TT;

    // staging map (LDS dest linear within buffer; source pre-swizzled)
    const bool isK = (w8 < 4);
    const int  cK = tid;
    const int  cV = tid - 256;
    const bf16* sBase = isK
        ? knb + (size_t)(cK >> 2) * RP + ((cK & 3) ^ ((cK >> 3) & 3)) * 8
        : vtb + (size_t)(cV >> 3) * TT + ((cV & 7) ^ ((cV >> 3) & 7)) * 8;
    const long long sStep = (long long)(isK ? RP : 1) * 64;  // per 64-row step
    const int ldsOff = isK ? w8 * 1024 : (w8 - 4) * 1024;

    // swizzled read offsets (in shorts)
    const int kslot = ((l16 >> 1) & 3);     // K frag: (quad^kslot)*8
    const int vswz  = (l16 & 7);            // V frag: ((ks*4+quad)^vswz)*8

    // paired tiles: A = bx (short), B = 15-bx (long); NTA < NTB always
    const int NTA = 2 * bx + 2, NTB = 32 - 2 * bx;
    const int qbaseA = bx * 128 + w8 * 16;
    const int qbaseB = (15 - bx) * 128 + w8 * 16;

    bf16x8 qfA = *(const bf16x8*)(qn + ((size_t)bh * TT + qbaseA + l16) * RP + quad * 8);
    bf16x8 qfB = *(const bf16x8*)(qn + ((size_t)bh * TT + qbaseB + l16) * RP + quad * 8);

    float lsumA = 0.f, lsumB = 0.f;
    f32x4 oA0 = (f32x4){0.f, 0.f, 0.f, 0.f};
    f32x4 oA1 = (f32x4){0.f, 0.f, 0.f, 0.f};
    f32x4 oB0 = (f32x4){0.f, 0.f, 0.f, 0.f};
    f32x4 oB1 = (f32x4){0.f, 0.f, 0.f, 0.f};

    // prologue: stage step 0 into buffer 0
    gl2lds16(sBase, (isK ? (char*)KsF[0] : (char*)VsF[0]) + ldsOff);
    int cur = 0;

    for (int st = 0; st < NTB; ++st) {
        asm volatile("s_waitcnt vmcnt(0)\n\ts_barrier" ::: "memory");

        const int nxt = cur ^ 1;
        gl2lds16(sBase + (long long)(st + 1) * sStep,
                 (isK ? (char*)KsF[nxt] : (char*)VsF[nxt]) + ldsOff);

        const int s0 = st * 64;
        const short* KsC = KsF[cur];
        const short* VsC = VsF[cur];

        ATTN_TILE(qfB, qbaseB, lsumB, oB0, oB1)
        if (st < NTA) {                        // block-uniform branch
            ATTN_TILE(qfA, qbaseA, lsumA, oA0, oA1)
        }
        cur = nxt;
    }

    ATTN_EPI(qbaseA, lsumA, oA0, oA1)
    ATTN_EPI(qbaseB, lsumB, oB0, oB1)
}

// ---------------------------------------------------------------------------
// Workspace (BYTE offsets from base = d_ws + 64):
//   xb    bf16 [0, 16777216)            (dead after gemm_qk)
//   wqT   bf16 [16777216, 18874368)     (dead after gemm_qk)
//   wkvT  bf16 [18874368, 19136512)     (dead after gemm_qk)
//   kvb   bf16 [19136512, 21233664)     (dead after gemm_kv)
//   att_b bf16 [0, 8388608)             (alias over dead xb lower half)
//   vTb   bf16 [8388608, 16777216)      (alias over dead xb upper half;
//                                        written directly by gemm_kv)
//   qn    bf16 [35913728, 44302336)
//   kn    bf16 [44302336, 52690944)     (attn tail prefetch -> old vb region,
//                                        harmless: mapped workspace)
//   wkwvT bf16 [61079552, 61341696)
//   woT   bf16 [61341696, 62390272)
// ---------------------------------------------------------------------------
extern "C" void kernel_launch(void* const* d_in, const int* in_sizes, int n_in,
                              void* d_out, int out_size, void* d_ws, size_t ws_size,
                              hipStream_t stream)
{
    float* out = (float*)d_out;
    const long long NOUT = (long long)BB * TT * DD;
    const int outgrid = (int)((NOUT + 255) / 256);

    static const long long expect[8] =
        {8388608, 1048576, 131072, 65536, 65536, 1048576, 64, 32};
    if (n_in != 8) {
        sentinel_kernel<<<outgrid, 256, 0, stream>>>(out, 20000.0f + 100.0f * n_in, NOUT);
        return;
    }
    for (int i = 0; i < 8; ++i) {
        if ((long long)in_sizes[i] != expect[i]) {
            sentinel_kernel<<<outgrid, 256, 0, stream>>>(out, 10000.0f + 1000.0f * i, NOUT);
            return;
        }
    }
    if (ws_size < 62914624ULL) {
        sentinel_kernel<<<outgrid, 256, 0, stream>>>(
            out, 30000.0f + (float)(ws_size >> 20), NOUT);
        return;
    }
    if (out_size != 8388608) {
        sentinel_kernel<<<outgrid, 256, 0, stream>>>(
            out, 512.0f * (1.0f + (float)(out_size >> 20)), NOUT);
        return;
    }

    const float* x   = (const float*)d_in[0];
    const float* Wq  = (const float*)d_in[1];
    const float* Wkv = (const float*)d_in[2];
    const float* Wk  = (const float*)d_in[3];
    const float* Wv  = (const float*)d_in[4];
    const float* Wo  = (const float*)d_in[5];
    const float* qg  = (const float*)d_in[6];
    const float* kg  = (const float*)d_in[7];

    char* base = (char*)d_ws + 64;
    bf16*  xb    = (bf16*)(base + 0);
    bf16*  wqT   = (bf16*)(base + 16777216);
    bf16*  wkvT  = (bf16*)(base + 18874368);
    bf16*  kvb   = (bf16*)(base + 19136512);
    bf16*  att_b = (bf16*)(base + 0);
    bf16*  vTb   = (bf16*)(base + 8388608);
    bf16*  qn    = (bf16*)(base + 35913728);
    bf16*  kn    = (bf16*)(base + 44302336);
    bf16*  wkwvT = (bf16*)(base + 61079552);
    bf16*  woT   = (bf16*)(base + 61341696);

    const int BT = BB * TT;                    // 8192

    // 1. ALL converts in one dispatch
    conv_all<<<9120, 256, 0, stream>>>(x, xb, Wq, wqT, Wkv, wkvT,
                                       Wk, Wv, wkwvT, Wo, woT);
    // 2. FUSED qrms-GEMM (512 blocks, XCD-swizzled) + kv GEMM (128 blocks)
    gemm_qk<<<640, 256, 0, stream>>>(
        (const short*)xb, (const short*)wqT, (const short*)wkvT, qn, kvb, qg);
    // 3. kn / vT = fused(kvb @ [Wk|Wv]) (K-RMS + transposed V, XCD-swizzled)
    gemm_kv<<<dim3(8, 64), 256, 0, stream>>>(
        (const short*)kvb, (const short*)wkwvT, kn, vTb, kg, BT, 2 * 512, LAT_);
    // 4. flash MFMA attention (paired-tile sweep, dbuf staging, __expf)
    attn_mfma<<<dim3(8, 64), 512, 0, stream>>>(qn, kn, vTb, att_b);
    // 5. out = att_b @ Wo_remap (MFMA, XCD-swizzled), 8192x1024, K=512
    gemm_mfma<float><<<dim3(8, 64), 256, 0, stream>>>(
        (const short*)att_b, (const short*)woT, out, BT, DD, 512);
}